// Round 2
// baseline (762.860 us; speedup 1.0000x reference)
//
#include <hip/hip_runtime.h>
#include <hip/hip_bf16.h>
#include <math.h>

#define NN 50000
#define NE 800000
#define ET (NE + NN)
#define HD 64
#define NEG 0.2f

typedef __hip_bfloat16 bf16;

// ---------------- CSR build ----------------
__global__ void zero_counts_k(int* __restrict__ c) {
  int i = blockIdx.x * 256 + threadIdx.x;
  if (i < NN) c[i] = 0;
}

__global__ void hist_k(const int* __restrict__ ei, int* __restrict__ counts) {
  int e = blockIdx.x * 256 + threadIdx.x;
  if (e >= ET) return;
  int d = (e < NE) ? ei[NE + e] : (e - NE);
  atomicAdd(&counts[d], 1);
}

__global__ void scan_k(const int* __restrict__ counts, int* __restrict__ offsets,
                       int* __restrict__ cursor) {
  __shared__ int sums[1024];
  int t = threadIdx.x;
  const int CH = (NN + 1023) / 1024;
  int lo = t * CH;
  int hi = min(lo + CH, NN);
  int s = 0;
  for (int i = lo; i < hi; ++i) s += counts[i];
  sums[t] = s;
  __syncthreads();
  for (int off = 1; off < 1024; off <<= 1) {
    int v = sums[t];
    int u = (t >= off) ? sums[t - off] : 0;
    __syncthreads();
    sums[t] = v + u;
    __syncthreads();
  }
  int base = (t == 0) ? 0 : sums[t - 1];
  for (int i = lo; i < hi; ++i) {
    offsets[i] = base;
    cursor[i] = base;
    base += counts[i];
  }
  if (t == 1023) offsets[NN] = sums[1023];
}

__global__ void scatter_k(const int* __restrict__ ei, int* __restrict__ cursor,
                          int* __restrict__ csr) {
  int e = blockIdx.x * 256 + threadIdx.x;
  if (e >= ET) return;
  int s, d;
  if (e < NE) { s = ei[e]; d = ei[NE + e]; } else { s = e - NE; d = s; }
  int pos = atomicAdd(&cursor[d], 1);
  csr[pos] = s;
}

// ---------------- fp32 tiled GEMM: C[M,N] = A[M,K] @ B[K,N] ----------------
__device__ inline void store_out(float* C, size_t i, float v) { C[i] = v; }
__device__ inline void store_out(bf16* C, size_t i, float v) { C[i] = __float2bfloat16(v); }

template <typename OT>
__global__ __launch_bounds__(256) void gemm_k(const float* __restrict__ A,
                                              const float* __restrict__ B,
                                              OT* __restrict__ C,
                                              int M, int N, int K) {
  const int BM = 64, BN = 64, BK = 32;
  __shared__ float As[BK][BM + 4];
  __shared__ float Bs[BK][BN];
  int bm = blockIdx.y * BM, bn = blockIdx.x * BN;
  int tx = threadIdx.x & 15, ty = threadIdx.x >> 4;
  float acc[4][4] = {};
  for (int k0 = 0; k0 < K; k0 += BK) {
    for (int i = threadIdx.x; i < BM * BK; i += 256) {
      int r = i >> 5, c = i & 31;
      int gr = bm + r;
      As[c][r] = (gr < M) ? A[(size_t)gr * K + k0 + c] : 0.f;
    }
    for (int i = threadIdx.x; i < BK * BN; i += 256) {
      int r = i >> 6, c = i & 63;
      Bs[r][c] = B[(size_t)(k0 + r) * N + bn + c];
    }
    __syncthreads();
#pragma unroll
    for (int k = 0; k < BK; ++k) {
      float a[4], b[4];
#pragma unroll
      for (int i = 0; i < 4; ++i) a[i] = As[k][ty * 4 + i];
#pragma unroll
      for (int j = 0; j < 4; ++j) b[j] = Bs[k][tx * 4 + j];
#pragma unroll
      for (int i = 0; i < 4; ++i)
#pragma unroll
        for (int j = 0; j < 4; ++j) acc[i][j] += a[i] * b[j];
    }
    __syncthreads();
  }
#pragma unroll
  for (int i = 0; i < 4; ++i) {
    int r = bm + ty * 4 + i;
    if (r < M) {
#pragma unroll
      for (int j = 0; j < 4; ++j)
        store_out(C, (size_t)r * N + bn + tx * 4 + j, acc[i][j]);
    }
  }
}

// ---------------- per-(node,head) attention dot products ----------------
template <int H>
__global__ void attdot_k(const bf16* __restrict__ h, const float* __restrict__ ws,
                         const float* __restrict__ wd, float* __restrict__ as_,
                         float* __restrict__ ad_) {
  int wid = blockIdx.x * 4 + (threadIdx.x >> 6);
  int lane = threadIdx.x & 63;
  if (wid >= NN * H) return;
  int n = wid / H, hd = wid % H;
  float v = __bfloat162float(h[(size_t)n * (H * HD) + hd * HD + lane]);
  float s = v * ws[hd * HD + lane];
  float d = v * wd[hd * HD + lane];
#pragma unroll
  for (int off = 32; off > 0; off >>= 1) {
    s += __shfl_xor(s, off);
    d += __shfl_xor(d, off);
  }
  if (lane == 0) {
    as_[wid] = s;
    ad_[wid] = d;
  }
}

// ---------------- GAT aggregation per destination node ----------------
// 4 waves/block; wave handles one (node, head). Lane = channel. Softmax is
// wave-parallel: lane e owns edge e of the current 64-edge chunk.
template <int H, int ACT>
__global__ __launch_bounds__(256) void gat_agg_k(
    const int* __restrict__ offsets, const int* __restrict__ csr,
    const bf16* __restrict__ h, const float* __restrict__ as_,
    const float* __restrict__ ad_, const float* __restrict__ bias,
    float* __restrict__ out) {
  const int wv = threadIdx.x >> 6, lane = threadIdx.x & 63;
  constexpr int NPB = 4 / H;
  int n = blockIdx.x * NPB + wv / H;
  int hd = wv % H;
  if (n >= NN) return;
  int beg = offsets[n], end = offsets[n + 1];
  float adn = ad_[(size_t)n * H + hd];
  float m = -1e30f, den = 0.f, acc = 0.f;
  for (int base = beg; base < end; base += 64) {
    int cnt = min(64, end - base);
    int src = 0;
    float l = -1e30f;
    if (lane < cnt) {
      src = csr[base + lane];
      float t = as_[(size_t)src * H + hd] + adn;
      l = (t > 0.f) ? t : NEG * t;
    }
    float mt = l;
#pragma unroll
    for (int off = 32; off; off >>= 1) mt = fmaxf(mt, __shfl_xor(mt, off));
    float mnew = fmaxf(m, mt);
    float ex = (lane < cnt) ? __expf(l - mnew) : 0.f;
    float s = ex;
#pragma unroll
    for (int off = 32; off; off >>= 1) s += __shfl_xor(s, off);
    float scale = __expf(m - mnew);
    den = den * scale + s;
    acc *= scale;
    m = mnew;
    for (int e = 0; e < cnt; ++e) {
      int se = __shfl(src, e);
      float we = __shfl(ex, e);
      acc += we * __bfloat162float(h[(size_t)se * (H * HD) + hd * HD + lane]);
    }
  }
  float res = acc / den + bias[hd * HD + lane];
  if (ACT) res = (res > 0.f) ? res : (__expf(res) - 1.f);
  out[(size_t)n * (H * HD) + hd * HD + lane] = res;
}

// ---------------- fused edge MLP: out[e] = relu(p[s]+q[d]+b1).w2 + b2 ------
__global__ void edge_out_k(const int* __restrict__ ei, const bf16* __restrict__ p,
                           const bf16* __restrict__ q, const float* __restrict__ mb1,
                           const float* __restrict__ w2, const float* __restrict__ mb2,
                           float* __restrict__ out) {
  int wid = blockIdx.x * 4 + (threadIdx.x >> 6);
  int lane = threadIdx.x & 63;
  if (wid >= NE) return;
  int s = ei[wid], d = ei[NE + wid];
  float v = __bfloat162float(p[(size_t)s * HD + lane]) +
            __bfloat162float(q[(size_t)d * HD + lane]) + mb1[lane];
  v = fmaxf(v, 0.f);
  float r = v * w2[lane];
#pragma unroll
  for (int off = 32; off > 0; off >>= 1) r += __shfl_xor(r, off);
  if (lane == 0) out[wid] = r + mb2[0];
}

extern "C" void kernel_launch(void* const* d_in, const int* in_sizes, int n_in,
                              void* d_out, int out_size, void* d_ws, size_t ws_size,
                              hipStream_t stream) {
  const float* x = (const float*)d_in[0];
  const int* ei = (const int*)d_in[1];
  const float* W1 = (const float*)d_in[2];
  const float* as1w = (const float*)d_in[3];
  const float* ad1w = (const float*)d_in[4];
  const float* b1 = (const float*)d_in[5];
  const float* W2 = (const float*)d_in[6];
  const float* as2w = (const float*)d_in[7];
  const float* ad2w = (const float*)d_in[8];
  const float* b2 = (const float*)d_in[9];
  const float* mw1 = (const float*)d_in[10];
  const float* mb1 = (const float*)d_in[11];
  const float* mw2 = (const float*)d_in[12];
  const float* mb2 = (const float*)d_in[13];
  float* out = (float*)d_out;

  char* ws = (char*)d_ws;
  size_t o = 0;
  auto alloc = [&](size_t bytes) {
    void* ptr = ws + o;
    o += (bytes + 255) & ~(size_t)255;
    return ptr;
  };
  int* counts = (int*)alloc((size_t)NN * 4);
  int* offsets = (int*)alloc((size_t)(NN + 1) * 4);
  int* cursor = (int*)alloc((size_t)NN * 4);
  int* csr = (int*)alloc((size_t)ET * 4);
  bf16* h1b = (bf16*)alloc((size_t)NN * 256 * 2);   // reused: h2b / pb / qb
  float* a_s1 = (float*)alloc((size_t)NN * 4 * 4);
  float* a_d1 = (float*)alloc((size_t)NN * 4 * 4);
  float* x2 = (float*)alloc((size_t)NN * 256 * 4);
  float* y = (float*)alloc((size_t)NN * 64 * 4);
  bf16* h2b = h1b;                 // first NN*64 bf16 of the region
  bf16* pb = h1b + (size_t)NN * 64;
  bf16* qb = h1b + (size_t)NN * 128;

  // CSR build (shared by both GAT layers; includes self loops)
  zero_counts_k<<<(NN + 255) / 256, 256, 0, stream>>>(counts);
  hist_k<<<(ET + 255) / 256, 256, 0, stream>>>(ei, counts);
  scan_k<<<1, 1024, 0, stream>>>(counts, offsets, cursor);
  scatter_k<<<(ET + 255) / 256, 256, 0, stream>>>(ei, cursor, csr);

  // Layer 1: h1 = x @ W1 (bf16 store); dots; aggregate -> x2 = elu(agg + b1)
  gemm_k<<<dim3(4, (NN + 63) / 64), 256, 0, stream>>>(x, W1, h1b, NN, 256, 128);
  attdot_k<4><<<NN, 256, 0, stream>>>(h1b, as1w, ad1w, a_s1, a_d1);
  gat_agg_k<4, 1><<<NN, 256, 0, stream>>>(offsets, csr, h1b, a_s1, a_d1, b1, x2);

  // Layer 2: h2 = x2 @ W2 (bf16); dots; aggregate -> y = agg + b2
  gemm_k<<<dim3(1, (NN + 63) / 64), 256, 0, stream>>>(x2, W2, h2b, NN, 64, 256);
  attdot_k<1><<<(NN + 3) / 4, 256, 0, stream>>>(h2b, as2w, ad2w, a_s1, a_d1);
  gat_agg_k<1, 0><<<(NN + 3) / 4, 256, 0, stream>>>(offsets, csr, h2b, a_s1, a_d1, b2, y);

  // Edge MLP decomposition: p = y @ mw1[:64], q = y @ mw1[64:]  (bf16 stores)
  gemm_k<<<dim3(1, (NN + 63) / 64), 256, 0, stream>>>(y, mw1, pb, NN, 64, 64);
  gemm_k<<<dim3(1, (NN + 63) / 64), 256, 0, stream>>>(y, mw1 + 64 * 64, qb, NN, 64, 64);

  // Final per-edge output
  edge_out_k<<<(NE + 3) / 4, 256, 0, stream>>>(ei, pb, qb, mb1, mw2, mb2, out);
}

// Round 3
// 521.953 us; speedup vs baseline: 1.4615x; 1.4615x over previous
//
#include <hip/hip_runtime.h>
#include <hip/hip_bf16.h>
#include <math.h>

#define NN 50000
#define NE 800000
#define ET (NE + NN)
#define HD 64
#define NEG 0.2f

typedef __hip_bfloat16 bf16;

__device__ __forceinline__ float bf2f(unsigned short u) {
  union { unsigned int i; float f; } c;
  c.i = ((unsigned int)u) << 16;
  return c.f;
}

// ---------------- CSR build ----------------
__global__ void zero_counts_k(int* __restrict__ c) {
  int i = blockIdx.x * 256 + threadIdx.x;
  if (i < NN) c[i] = 0;
}

__global__ void hist_k(const int* __restrict__ ei, int* __restrict__ counts) {
  int e = blockIdx.x * 256 + threadIdx.x;
  if (e >= ET) return;
  int d = (e < NE) ? ei[NE + e] : (e - NE);
  atomicAdd(&counts[d], 1);
}

__global__ void scan_k(const int* __restrict__ counts, int* __restrict__ offsets,
                       int* __restrict__ cursor) {
  __shared__ int sums[1024];
  int t = threadIdx.x;
  const int CH = (NN + 1023) / 1024;
  int lo = t * CH;
  int hi = min(lo + CH, NN);
  int s = 0;
  for (int i = lo; i < hi; ++i) s += counts[i];
  sums[t] = s;
  __syncthreads();
  for (int off = 1; off < 1024; off <<= 1) {
    int v = sums[t];
    int u = (t >= off) ? sums[t - off] : 0;
    __syncthreads();
    sums[t] = v + u;
    __syncthreads();
  }
  int base = (t == 0) ? 0 : sums[t - 1];
  for (int i = lo; i < hi; ++i) {
    offsets[i] = base;
    cursor[i] = base;
    base += counts[i];
  }
  if (t == 1023) offsets[NN] = sums[1023];
}

__global__ void scatter_k(const int* __restrict__ ei, int* __restrict__ cursor,
                          int* __restrict__ csr) {
  int e = blockIdx.x * 256 + threadIdx.x;
  if (e >= ET) return;
  int s, d;
  if (e < NE) { s = ei[e]; d = ei[NE + e]; } else { s = e - NE; d = s; }
  int pos = atomicAdd(&cursor[d], 1);
  csr[pos] = s;
}

// ---------------- fp32 tiled GEMM with optional fused attention dots -------
// C[M,N] = A[M,K] @ B[K,N].  When DOTS, N-block == 64 == one head: epilogue
// computes as_[row*H+head] = sum_c acc*ws, ad_ likewise (from fp32 acc).
__device__ __forceinline__ void store_out(float* C, size_t i, float v) { C[i] = v; }
__device__ __forceinline__ void store_out(bf16* C, size_t i, float v) { C[i] = __float2bfloat16(v); }

template <typename OT, int DOTS>
__global__ __launch_bounds__(256) void gemm_k(const float* __restrict__ A,
                                              const float* __restrict__ B,
                                              OT* __restrict__ C,
                                              int M, int N, int K,
                                              int ldc, int coff,
                                              const float* __restrict__ ws,
                                              const float* __restrict__ wd,
                                              float* __restrict__ as_,
                                              float* __restrict__ ad_, int H) {
  const int BM = 64, BN = 64, BK = 32;
  __shared__ float As[BK][BM + 4];
  __shared__ float Bs[BK][BN];
  int bm = blockIdx.y * BM, bn = blockIdx.x * BN;
  int tx = threadIdx.x & 15, ty = threadIdx.x >> 4;
  float acc[4][4] = {};
  for (int k0 = 0; k0 < K; k0 += BK) {
    for (int i = threadIdx.x; i < BM * BK; i += 256) {
      int r = i >> 5, c = i & 31;
      int gr = bm + r;
      As[c][r] = (gr < M) ? A[(size_t)gr * K + k0 + c] : 0.f;
    }
    for (int i = threadIdx.x; i < BK * BN; i += 256) {
      int r = i >> 6, c = i & 63;
      Bs[r][c] = B[(size_t)(k0 + r) * N + bn + c];
    }
    __syncthreads();
#pragma unroll
    for (int k = 0; k < BK; ++k) {
      float a[4], b[4];
#pragma unroll
      for (int i = 0; i < 4; ++i) a[i] = As[k][ty * 4 + i];
#pragma unroll
      for (int j = 0; j < 4; ++j) b[j] = Bs[k][tx * 4 + j];
#pragma unroll
      for (int i = 0; i < 4; ++i)
#pragma unroll
        for (int j = 0; j < 4; ++j) acc[i][j] += a[i] * b[j];
    }
    __syncthreads();
  }
#pragma unroll
  for (int i = 0; i < 4; ++i) {
    int r = bm + ty * 4 + i;
    if (r < M) {
#pragma unroll
      for (int j = 0; j < 4; ++j)
        store_out(C, (size_t)r * ldc + coff + bn + tx * 4 + j, acc[i][j]);
    }
  }
  if (DOTS) {
    int head = blockIdx.x;  // BN==64==head width
    float ps[4], pd[4];
#pragma unroll
    for (int i = 0; i < 4; ++i) {
      float s = 0.f, d = 0.f;
#pragma unroll
      for (int j = 0; j < 4; ++j) {
        float wsv = ws[head * 64 + tx * 4 + j];
        float wdv = wd[head * 64 + tx * 4 + j];
        s += acc[i][j] * wsv;
        d += acc[i][j] * wdv;
      }
      ps[i] = s; pd[i] = d;
    }
#pragma unroll
    for (int off = 8; off; off >>= 1) {
#pragma unroll
      for (int i = 0; i < 4; ++i) {
        ps[i] += __shfl_xor(ps[i], off);
        pd[i] += __shfl_xor(pd[i], off);
      }
    }
    if (tx == 0) {
#pragma unroll
      for (int i = 0; i < 4; ++i) {
        int r = bm + ty * 4 + i;
        if (r < M) {
          as_[(size_t)r * H + head] = ps[i];
          ad_[(size_t)r * H + head] = pd[i];
        }
      }
    }
  }
}

// ---------------- GAT layer-1 aggregation: 1 wave per node, 4 heads -------
// Lane covers 4 channels (ushort4), head = lane>>4. Chunk softmax: lane=edge,
// float4 logits (4 heads); exp weights + srcs staged in wave-private LDS.
__global__ __launch_bounds__(256) void gat_agg4_k(
    const int* __restrict__ offsets, const int* __restrict__ csr,
    const bf16* __restrict__ h, const float* __restrict__ as_,
    const float* __restrict__ ad_, const float* __restrict__ bias,
    float* __restrict__ out) {
  __shared__ float exs[4][64][4];
  __shared__ int srcs[4][64];
  int wv = threadIdx.x >> 6, lane = threadIdx.x & 63;
  int n = blockIdx.x * 4 + wv;
  int hd = lane >> 4;
  int beg = offsets[n], end = offsets[n + 1];
  float4 adn = *(const float4*)(ad_ + (size_t)n * 4);
  float m0 = -1e30f, m1 = -1e30f, m2 = -1e30f, m3 = -1e30f;
  float d0 = 0.f, d1 = 0.f, d2 = 0.f, d3 = 0.f;
  float4 acc = {0.f, 0.f, 0.f, 0.f};
  for (int base = beg; base < end; base += 64) {
    int cnt = min(64, end - base);
    int src = 0;
    float l0 = -1e30f, l1 = -1e30f, l2 = -1e30f, l3 = -1e30f;
    if (lane < cnt) {
      src = csr[base + lane];
      float4 a4 = *(const float4*)(as_ + (size_t)src * 4);
      float t;
      t = a4.x + adn.x; l0 = (t > 0.f) ? t : NEG * t;
      t = a4.y + adn.y; l1 = (t > 0.f) ? t : NEG * t;
      t = a4.z + adn.z; l2 = (t > 0.f) ? t : NEG * t;
      t = a4.w + adn.w; l3 = (t > 0.f) ? t : NEG * t;
    }
    float t0 = l0, t1 = l1, t2 = l2, t3 = l3;
#pragma unroll
    for (int off = 32; off; off >>= 1) {
      t0 = fmaxf(t0, __shfl_xor(t0, off));
      t1 = fmaxf(t1, __shfl_xor(t1, off));
      t2 = fmaxf(t2, __shfl_xor(t2, off));
      t3 = fmaxf(t3, __shfl_xor(t3, off));
    }
    float M0 = fmaxf(m0, t0), M1 = fmaxf(m1, t1), M2 = fmaxf(m2, t2), M3 = fmaxf(m3, t3);
    float e0 = 0.f, e1 = 0.f, e2 = 0.f, e3 = 0.f;
    if (lane < cnt) {
      e0 = __expf(l0 - M0); e1 = __expf(l1 - M1);
      e2 = __expf(l2 - M2); e3 = __expf(l3 - M3);
    }
    float s0 = e0, s1 = e1, s2 = e2, s3 = e3;
#pragma unroll
    for (int off = 32; off; off >>= 1) {
      s0 += __shfl_xor(s0, off);
      s1 += __shfl_xor(s1, off);
      s2 += __shfl_xor(s2, off);
      s3 += __shfl_xor(s3, off);
    }
    float sc0 = __expf(m0 - M0), sc1 = __expf(m1 - M1);
    float sc2 = __expf(m2 - M2), sc3 = __expf(m3 - M3);
    d0 = d0 * sc0 + s0; d1 = d1 * sc1 + s1;
    d2 = d2 * sc2 + s2; d3 = d3 * sc3 + s3;
    m0 = M0; m1 = M1; m2 = M2; m3 = M3;
    float mysc = (hd == 0) ? sc0 : (hd == 1) ? sc1 : (hd == 2) ? sc2 : sc3;
    acc.x *= mysc; acc.y *= mysc; acc.z *= mysc; acc.w *= mysc;
    float4 ex4 = {e0, e1, e2, e3};
    *(float4*)(&exs[wv][lane][0]) = ex4;
    srcs[wv][lane] = src;
    __builtin_amdgcn_wave_barrier();
    int e = 0;
    for (; e + 4 <= cnt; e += 4) {
      int si0 = srcs[wv][e], si1 = srcs[wv][e + 1];
      int si2 = srcs[wv][e + 2], si3 = srcs[wv][e + 3];
      float w0 = exs[wv][e][hd], w1 = exs[wv][e + 1][hd];
      float w2 = exs[wv][e + 2][hd], w3 = exs[wv][e + 3][hd];
      ushort4 r0 = *(const ushort4*)(h + (size_t)si0 * 256 + lane * 4);
      ushort4 r1 = *(const ushort4*)(h + (size_t)si1 * 256 + lane * 4);
      ushort4 r2 = *(const ushort4*)(h + (size_t)si2 * 256 + lane * 4);
      ushort4 r3 = *(const ushort4*)(h + (size_t)si3 * 256 + lane * 4);
      acc.x += w0 * bf2f(r0.x); acc.y += w0 * bf2f(r0.y);
      acc.z += w0 * bf2f(r0.z); acc.w += w0 * bf2f(r0.w);
      acc.x += w1 * bf2f(r1.x); acc.y += w1 * bf2f(r1.y);
      acc.z += w1 * bf2f(r1.z); acc.w += w1 * bf2f(r1.w);
      acc.x += w2 * bf2f(r2.x); acc.y += w2 * bf2f(r2.y);
      acc.z += w2 * bf2f(r2.z); acc.w += w2 * bf2f(r2.w);
      acc.x += w3 * bf2f(r3.x); acc.y += w3 * bf2f(r3.y);
      acc.z += w3 * bf2f(r3.z); acc.w += w3 * bf2f(r3.w);
    }
    for (; e < cnt; ++e) {
      int si = srcs[wv][e];
      float w = exs[wv][e][hd];
      ushort4 r = *(const ushort4*)(h + (size_t)si * 256 + lane * 4);
      acc.x += w * bf2f(r.x); acc.y += w * bf2f(r.y);
      acc.z += w * bf2f(r.z); acc.w += w * bf2f(r.w);
    }
  }
  float myden = (hd == 0) ? d0 : (hd == 1) ? d1 : (hd == 2) ? d2 : d3;
  float4 b4 = *(const float4*)(bias + lane * 4);
  float4 res;
  res.x = acc.x / myden + b4.x;
  res.y = acc.y / myden + b4.y;
  res.z = acc.z / myden + b4.z;
  res.w = acc.w / myden + b4.w;
  res.x = (res.x > 0.f) ? res.x : (__expf(res.x) - 1.f);
  res.y = (res.y > 0.f) ? res.y : (__expf(res.y) - 1.f);
  res.z = (res.z > 0.f) ? res.z : (__expf(res.z) - 1.f);
  res.w = (res.w > 0.f) ? res.w : (__expf(res.w) - 1.f);
  *(float4*)(out + (size_t)n * 256 + lane * 4) = res;
}

// ---------------- GAT layer-2 aggregation: 1 wave per node, H=1 ----------
// Wave processes 2 edges per step: slot=lane>>5 picks the edge, cp=lane&31
// covers 2 channels (ushort2). Partials combined via shfl_xor(32).
__global__ __launch_bounds__(256) void gat_agg1_k(
    const int* __restrict__ offsets, const int* __restrict__ csr,
    const bf16* __restrict__ h, const float* __restrict__ as_,
    const float* __restrict__ ad_, const float* __restrict__ bias,
    float* __restrict__ out) {
  __shared__ float exs[4][64];
  __shared__ int srcs[4][64];
  int wv = threadIdx.x >> 6, lane = threadIdx.x & 63;
  int n = blockIdx.x * 4 + wv;
  int slot = lane >> 5, cp = lane & 31;
  int beg = offsets[n], end = offsets[n + 1];
  float adn = ad_[n];
  float m = -1e30f, den = 0.f;
  float ax = 0.f, ay = 0.f;
  for (int base = beg; base < end; base += 64) {
    int cnt = min(64, end - base);
    int src = 0;
    float l = -1e30f;
    if (lane < cnt) {
      src = csr[base + lane];
      float t = as_[src] + adn;
      l = (t > 0.f) ? t : NEG * t;
    }
    float mt = l;
#pragma unroll
    for (int off = 32; off; off >>= 1) mt = fmaxf(mt, __shfl_xor(mt, off));
    float M = fmaxf(m, mt);
    float ex = (lane < cnt) ? __expf(l - M) : 0.f;
    float s = ex;
#pragma unroll
    for (int off = 32; off; off >>= 1) s += __shfl_xor(s, off);
    float sc = __expf(m - M);
    den = den * sc + s;
    m = M;
    ax *= sc; ay *= sc;
    exs[wv][lane] = ex;
    srcs[wv][lane] = src;
    __builtin_amdgcn_wave_barrier();
    int e = 0;
    for (; e + 8 <= cnt; e += 8) {
      int i0 = e + slot, i1 = e + 2 + slot, i2 = e + 4 + slot, i3 = e + 6 + slot;
      int si0 = srcs[wv][i0], si1 = srcs[wv][i1], si2 = srcs[wv][i2], si3 = srcs[wv][i3];
      float w0 = exs[wv][i0], w1 = exs[wv][i1], w2 = exs[wv][i2], w3 = exs[wv][i3];
      ushort2 r0 = *(const ushort2*)(h + (size_t)si0 * 64 + cp * 2);
      ushort2 r1 = *(const ushort2*)(h + (size_t)si1 * 64 + cp * 2);
      ushort2 r2 = *(const ushort2*)(h + (size_t)si2 * 64 + cp * 2);
      ushort2 r3 = *(const ushort2*)(h + (size_t)si3 * 64 + cp * 2);
      ax += w0 * bf2f(r0.x); ay += w0 * bf2f(r0.y);
      ax += w1 * bf2f(r1.x); ay += w1 * bf2f(r1.y);
      ax += w2 * bf2f(r2.x); ay += w2 * bf2f(r2.y);
      ax += w3 * bf2f(r3.x); ay += w3 * bf2f(r3.y);
    }
    for (; e < cnt; e += 2) {
      int i = e + slot;
      int ok = (i < cnt);
      int si = srcs[wv][ok ? i : 0];
      float w = ok ? exs[wv][i] : 0.f;
      ushort2 r = *(const ushort2*)(h + (size_t)si * 64 + cp * 2);
      ax += w * bf2f(r.x); ay += w * bf2f(r.y);
    }
  }
  ax += __shfl_xor(ax, 32);
  ay += __shfl_xor(ay, 32);
  if (slot == 0) {
    float2 res;
    res.x = ax / den + bias[cp * 2];
    res.y = ay / den + bias[cp * 2 + 1];
    *(float2*)(out + (size_t)n * 64 + cp * 2) = res;
  }
}

// ---------------- fused edge MLP: 2 edges per wave ------------------------
__global__ __launch_bounds__(256) void edge_out_k(
    const int* __restrict__ ei, const bf16* __restrict__ pq,
    const float* __restrict__ mb1, const float* __restrict__ w2,
    const float* __restrict__ mb2, float* __restrict__ out) {
  int wid = blockIdx.x * 4 + (threadIdx.x >> 6);
  int lane = threadIdx.x & 63;
  int slot = lane >> 5, cp = lane & 31;
  int e = wid * 2 + slot;
  if (e >= NE) return;
  int s = ei[e], d = ei[NE + e];
  ushort2 rp = *(const ushort2*)(pq + (size_t)s * 128 + cp * 2);
  ushort2 rq = *(const ushort2*)(pq + (size_t)d * 128 + 64 + cp * 2);
  float2 mb = *(const float2*)(mb1 + cp * 2);
  float2 wv2 = *(const float2*)(w2 + cp * 2);
  float v0 = bf2f(rp.x) + bf2f(rq.x) + mb.x;
  float v1 = bf2f(rp.y) + bf2f(rq.y) + mb.y;
  v0 = fmaxf(v0, 0.f);
  v1 = fmaxf(v1, 0.f);
  float r = v0 * wv2.x + v1 * wv2.y;
#pragma unroll
  for (int off = 16; off; off >>= 1) r += __shfl_xor(r, off);
  if (cp == 0) out[e] = r + mb2[0];
}

extern "C" void kernel_launch(void* const* d_in, const int* in_sizes, int n_in,
                              void* d_out, int out_size, void* d_ws, size_t ws_size,
                              hipStream_t stream) {
  const float* x = (const float*)d_in[0];
  const int* ei = (const int*)d_in[1];
  const float* W1 = (const float*)d_in[2];
  const float* as1w = (const float*)d_in[3];
  const float* ad1w = (const float*)d_in[4];
  const float* b1 = (const float*)d_in[5];
  const float* W2 = (const float*)d_in[6];
  const float* as2w = (const float*)d_in[7];
  const float* ad2w = (const float*)d_in[8];
  const float* b2 = (const float*)d_in[9];
  const float* mw1 = (const float*)d_in[10];
  const float* mb1 = (const float*)d_in[11];
  const float* mw2 = (const float*)d_in[12];
  const float* mb2 = (const float*)d_in[13];
  float* out = (float*)d_out;

  char* ws = (char*)d_ws;
  size_t o = 0;
  auto alloc = [&](size_t bytes) {
    void* ptr = ws + o;
    o += (bytes + 255) & ~(size_t)255;
    return ptr;
  };
  int* counts = (int*)alloc((size_t)NN * 4);
  int* offsets = (int*)alloc((size_t)(NN + 1) * 4);
  int* cursor = (int*)alloc((size_t)NN * 4);
  int* csr = (int*)alloc((size_t)ET * 4);
  bf16* h1b = (bf16*)alloc((size_t)NN * 256 * 2);   // reused: h2b / pq
  float* a_s1 = (float*)alloc((size_t)NN * 4 * 4);
  float* a_d1 = (float*)alloc((size_t)NN * 4 * 4);
  float* x2 = (float*)alloc((size_t)NN * 256 * 4);
  float* y = (float*)alloc((size_t)NN * 64 * 4);
  bf16* h2b = h1b;                        // NN*64 bf16
  bf16* pq = h1b + (size_t)NN * 64;       // NN*128 bf16, interleaved [p|q]

  // CSR build (shared by both GAT layers; includes self loops)
  zero_counts_k<<<(NN + 255) / 256, 256, 0, stream>>>(counts);
  hist_k<<<(ET + 255) / 256, 256, 0, stream>>>(ei, counts);
  scan_k<<<1, 1024, 0, stream>>>(counts, offsets, cursor);
  scatter_k<<<(ET + 255) / 256, 256, 0, stream>>>(ei, cursor, csr);

  // Layer 1: h1 = x @ W1 (bf16) + fused attention dots; aggregate -> x2
  gemm_k<bf16, 1><<<dim3(4, (NN + 63) / 64), 256, 0, stream>>>(
      x, W1, h1b, NN, 256, 128, 256, 0, as1w, ad1w, a_s1, a_d1, 4);
  gat_agg4_k<<<NN / 4, 256, 0, stream>>>(offsets, csr, h1b, a_s1, a_d1, b1, x2);

  // Layer 2: h2 = x2 @ W2 (bf16) + fused dots; aggregate -> y
  gemm_k<bf16, 1><<<dim3(1, (NN + 63) / 64), 256, 0, stream>>>(
      x2, W2, h2b, NN, 64, 256, 64, 0, as2w, ad2w, a_s1, a_d1, 1);
  gat_agg1_k<<<NN / 4, 256, 0, stream>>>(offsets, csr, h2b, a_s1, a_d1, b2, y);

  // Edge MLP decomposition: pq[:, :64] = y @ mw1[:64], pq[:, 64:] = y @ mw1[64:]
  gemm_k<bf16, 0><<<dim3(1, (NN + 63) / 64), 256, 0, stream>>>(
      y, mw1, pq, NN, 64, 64, 128, 0, nullptr, nullptr, nullptr, nullptr, 0);
  gemm_k<bf16, 0><<<dim3(1, (NN + 63) / 64), 256, 0, stream>>>(
      y, mw1 + 64 * 64, pq, NN, 64, 64, 128, 64, nullptr, nullptr, nullptr, nullptr, 0);

  // Final per-edge output
  edge_out_k<<<(NE / 2 + 3) / 4, 256, 0, stream>>>(ei, pq, mb1, mw2, mb2, out);
}

// Round 4
// 411.555 us; speedup vs baseline: 1.8536x; 1.2682x over previous
//
#include <hip/hip_runtime.h>
#include <hip/hip_bf16.h>
#include <math.h>

#define NN 50000
#define NE 800000
#define ET (NE + NN)
#define HD 64
#define NEG 0.2f
#define NB ((NN + 255) / 256)

typedef __hip_bfloat16 bf16;

__device__ __forceinline__ float bf2f(unsigned short u) {
  union { unsigned int i; float f; } c;
  c.i = ((unsigned int)u) << 16;
  return c.f;
}

// ---------------- CSR build ----------------
__global__ void zero_counts_k(int* __restrict__ c) {
  int i = blockIdx.x * 256 + threadIdx.x;
  if (i < NN) c[i] = 0;
}

__global__ void hist_k(const int* __restrict__ ei, int* __restrict__ counts) {
  int e = blockIdx.x * 256 + threadIdx.x;
  if (e >= ET) return;
  int d = (e < NE) ? ei[NE + e] : (e - NE);
  atomicAdd(&counts[d], 1);
}

// parallel scan, step 1: per-block sums
__global__ __launch_bounds__(256) void scan_bsum_k(const int* __restrict__ counts,
                                                   int* __restrict__ bsums) {
  __shared__ int wsum[4];
  int i = blockIdx.x * 256 + threadIdx.x;
  int v = (i < NN) ? counts[i] : 0;
#pragma unroll
  for (int off = 32; off; off >>= 1) v += __shfl_xor(v, off);
  if ((threadIdx.x & 63) == 0) wsum[threadIdx.x >> 6] = v;
  __syncthreads();
  if (threadIdx.x == 0) bsums[blockIdx.x] = wsum[0] + wsum[1] + wsum[2] + wsum[3];
}

// step 2: single block scans the block sums -> exclusive prefixes (in place)
__global__ __launch_bounds__(256) void scan_top_k(int* __restrict__ bsums) {
  __shared__ int s[256];
  int t = threadIdx.x;
  int v = (t < NB) ? bsums[t] : 0;
  s[t] = v;
  __syncthreads();
  for (int off = 1; off < 256; off <<= 1) {
    int u = (t >= off) ? s[t - off] : 0;
    __syncthreads();
    s[t] += u;
    __syncthreads();
  }
  if (t < NB) bsums[t] = s[t] - v;  // exclusive
}

// step 3: block-local scan + block prefix -> offsets & cursor
__global__ __launch_bounds__(256) void scan_final_k(const int* __restrict__ counts,
                                                    const int* __restrict__ bsums,
                                                    int* __restrict__ offsets,
                                                    int* __restrict__ cursor) {
  __shared__ int s[256];
  int t = threadIdx.x;
  int i = blockIdx.x * 256 + t;
  int v = (i < NN) ? counts[i] : 0;
  s[t] = v;
  __syncthreads();
  for (int off = 1; off < 256; off <<= 1) {
    int u = (t >= off) ? s[t - off] : 0;
    __syncthreads();
    s[t] += u;
    __syncthreads();
  }
  int excl = s[t] - v + bsums[blockIdx.x];
  if (i < NN) {
    offsets[i] = excl;
    cursor[i] = excl;
    if (i == NN - 1) offsets[NN] = excl + v;
  }
}

__global__ void scatter_k(const int* __restrict__ ei, int* __restrict__ cursor,
                          int* __restrict__ csr) {
  int e = blockIdx.x * 256 + threadIdx.x;
  if (e >= ET) return;
  int s, d;
  if (e < NE) { s = ei[e]; d = ei[NE + e]; } else { s = e - NE; d = s; }
  int pos = atomicAdd(&cursor[d], 1);
  csr[pos] = s;
}

// ---------------- fp32 tiled GEMM with optional fused attention dots -------
__device__ __forceinline__ void store_out(float* C, size_t i, float v) { C[i] = v; }
__device__ __forceinline__ void store_out(bf16* C, size_t i, float v) { C[i] = __float2bfloat16(v); }

template <typename OT, int DOTS>
__global__ __launch_bounds__(256) void gemm_k(const float* __restrict__ A,
                                              const float* __restrict__ B,
                                              OT* __restrict__ C,
                                              int M, int N, int K,
                                              int ldc, int coff,
                                              const float* __restrict__ ws,
                                              const float* __restrict__ wd,
                                              float* __restrict__ as_,
                                              float* __restrict__ ad_, int H) {
  const int BM = 64, BN = 64, BK = 32;
  __shared__ float As[BK][BM + 4];
  __shared__ float Bs[BK][BN];
  int bm = blockIdx.y * BM, bn = blockIdx.x * BN;
  int tx = threadIdx.x & 15, ty = threadIdx.x >> 4;
  float acc[4][4] = {};
  for (int k0 = 0; k0 < K; k0 += BK) {
    for (int i = threadIdx.x; i < BM * BK; i += 256) {
      int r = i >> 5, c = i & 31;
      int gr = bm + r;
      As[c][r] = (gr < M) ? A[(size_t)gr * K + k0 + c] : 0.f;
    }
    for (int i = threadIdx.x; i < BK * BN; i += 256) {
      int r = i >> 6, c = i & 63;
      Bs[r][c] = B[(size_t)(k0 + r) * N + bn + c];
    }
    __syncthreads();
#pragma unroll
    for (int k = 0; k < BK; ++k) {
      float a[4], b[4];
#pragma unroll
      for (int i = 0; i < 4; ++i) a[i] = As[k][ty * 4 + i];
#pragma unroll
      for (int j = 0; j < 4; ++j) b[j] = Bs[k][tx * 4 + j];
#pragma unroll
      for (int i = 0; i < 4; ++i)
#pragma unroll
        for (int j = 0; j < 4; ++j) acc[i][j] += a[i] * b[j];
    }
    __syncthreads();
  }
#pragma unroll
  for (int i = 0; i < 4; ++i) {
    int r = bm + ty * 4 + i;
    if (r < M) {
#pragma unroll
      for (int j = 0; j < 4; ++j)
        store_out(C, (size_t)r * ldc + coff + bn + tx * 4 + j, acc[i][j]);
    }
  }
  if (DOTS) {
    int head = blockIdx.x;  // BN==64==head width
    float ps[4], pd[4];
#pragma unroll
    for (int i = 0; i < 4; ++i) {
      float s = 0.f, d = 0.f;
#pragma unroll
      for (int j = 0; j < 4; ++j) {
        float wsv = ws[head * 64 + tx * 4 + j];
        float wdv = wd[head * 64 + tx * 4 + j];
        s += acc[i][j] * wsv;
        d += acc[i][j] * wdv;
      }
      ps[i] = s; pd[i] = d;
    }
#pragma unroll
    for (int off = 8; off; off >>= 1) {
#pragma unroll
      for (int i = 0; i < 4; ++i) {
        ps[i] += __shfl_xor(ps[i], off);
        pd[i] += __shfl_xor(pd[i], off);
      }
    }
    if (tx == 0) {
#pragma unroll
      for (int i = 0; i < 4; ++i) {
        int r = bm + ty * 4 + i;
        if (r < M) {
          as_[(size_t)r * H + head] = ps[i];
          ad_[(size_t)r * H + head] = pd[i];
        }
      }
    }
  }
}

// ---------------- GAT layer-1 aggregation: 1 wave per node, 4 heads -------
__global__ __launch_bounds__(256) void gat_agg4_k(
    const int* __restrict__ offsets, const int* __restrict__ csr,
    const bf16* __restrict__ h, const float* __restrict__ as_,
    const float* __restrict__ ad_, const float* __restrict__ bias,
    float* __restrict__ out) {
  __shared__ float exs[4][64][4];
  __shared__ int srcs[4][64];
  int wv = threadIdx.x >> 6, lane = threadIdx.x & 63;
  int n = blockIdx.x * 4 + wv;
  int hd = lane >> 4;
  int beg = offsets[n], end = offsets[n + 1];
  float4 adn = *(const float4*)(ad_ + (size_t)n * 4);
  float m0 = -1e30f, m1 = -1e30f, m2 = -1e30f, m3 = -1e30f;
  float d0 = 0.f, d1 = 0.f, d2 = 0.f, d3 = 0.f;
  float4 acc = {0.f, 0.f, 0.f, 0.f};
  for (int base = beg; base < end; base += 64) {
    int cnt = min(64, end - base);
    int src = 0;
    float l0 = -1e30f, l1 = -1e30f, l2 = -1e30f, l3 = -1e30f;
    if (lane < cnt) {
      src = csr[base + lane];
      float4 a4 = *(const float4*)(as_ + (size_t)src * 4);
      float t;
      t = a4.x + adn.x; l0 = (t > 0.f) ? t : NEG * t;
      t = a4.y + adn.y; l1 = (t > 0.f) ? t : NEG * t;
      t = a4.z + adn.z; l2 = (t > 0.f) ? t : NEG * t;
      t = a4.w + adn.w; l3 = (t > 0.f) ? t : NEG * t;
    }
    float t0 = l0, t1 = l1, t2 = l2, t3 = l3;
#pragma unroll
    for (int off = 32; off; off >>= 1) {
      t0 = fmaxf(t0, __shfl_xor(t0, off));
      t1 = fmaxf(t1, __shfl_xor(t1, off));
      t2 = fmaxf(t2, __shfl_xor(t2, off));
      t3 = fmaxf(t3, __shfl_xor(t3, off));
    }
    float M0 = fmaxf(m0, t0), M1 = fmaxf(m1, t1), M2 = fmaxf(m2, t2), M3 = fmaxf(m3, t3);
    float e0 = 0.f, e1 = 0.f, e2 = 0.f, e3 = 0.f;
    if (lane < cnt) {
      e0 = __expf(l0 - M0); e1 = __expf(l1 - M1);
      e2 = __expf(l2 - M2); e3 = __expf(l3 - M3);
    }
    float s0 = e0, s1 = e1, s2 = e2, s3 = e3;
#pragma unroll
    for (int off = 32; off; off >>= 1) {
      s0 += __shfl_xor(s0, off);
      s1 += __shfl_xor(s1, off);
      s2 += __shfl_xor(s2, off);
      s3 += __shfl_xor(s3, off);
    }
    float sc0 = __expf(m0 - M0), sc1 = __expf(m1 - M1);
    float sc2 = __expf(m2 - M2), sc3 = __expf(m3 - M3);
    d0 = d0 * sc0 + s0; d1 = d1 * sc1 + s1;
    d2 = d2 * sc2 + s2; d3 = d3 * sc3 + s3;
    m0 = M0; m1 = M1; m2 = M2; m3 = M3;
    float mysc = (hd == 0) ? sc0 : (hd == 1) ? sc1 : (hd == 2) ? sc2 : sc3;
    acc.x *= mysc; acc.y *= mysc; acc.z *= mysc; acc.w *= mysc;
    float4 ex4 = {e0, e1, e2, e3};
    *(float4*)(&exs[wv][lane][0]) = ex4;
    srcs[wv][lane] = src;
    __builtin_amdgcn_wave_barrier();
    int e = 0;
    for (; e + 4 <= cnt; e += 4) {
      int si0 = srcs[wv][e], si1 = srcs[wv][e + 1];
      int si2 = srcs[wv][e + 2], si3 = srcs[wv][e + 3];
      float w0 = exs[wv][e][hd], w1 = exs[wv][e + 1][hd];
      float w2 = exs[wv][e + 2][hd], w3 = exs[wv][e + 3][hd];
      ushort4 r0 = *(const ushort4*)(h + (size_t)si0 * 256 + lane * 4);
      ushort4 r1 = *(const ushort4*)(h + (size_t)si1 * 256 + lane * 4);
      ushort4 r2 = *(const ushort4*)(h + (size_t)si2 * 256 + lane * 4);
      ushort4 r3 = *(const ushort4*)(h + (size_t)si3 * 256 + lane * 4);
      acc.x += w0 * bf2f(r0.x); acc.y += w0 * bf2f(r0.y);
      acc.z += w0 * bf2f(r0.z); acc.w += w0 * bf2f(r0.w);
      acc.x += w1 * bf2f(r1.x); acc.y += w1 * bf2f(r1.y);
      acc.z += w1 * bf2f(r1.z); acc.w += w1 * bf2f(r1.w);
      acc.x += w2 * bf2f(r2.x); acc.y += w2 * bf2f(r2.y);
      acc.z += w2 * bf2f(r2.z); acc.w += w2 * bf2f(r2.w);
      acc.x += w3 * bf2f(r3.x); acc.y += w3 * bf2f(r3.y);
      acc.z += w3 * bf2f(r3.z); acc.w += w3 * bf2f(r3.w);
    }
    for (; e < cnt; ++e) {
      int si = srcs[wv][e];
      float w = exs[wv][e][hd];
      ushort4 r = *(const ushort4*)(h + (size_t)si * 256 + lane * 4);
      acc.x += w * bf2f(r.x); acc.y += w * bf2f(r.y);
      acc.z += w * bf2f(r.z); acc.w += w * bf2f(r.w);
    }
  }
  float myden = (hd == 0) ? d0 : (hd == 1) ? d1 : (hd == 2) ? d2 : d3;
  float4 b4 = *(const float4*)(bias + lane * 4);
  float4 res;
  res.x = acc.x / myden + b4.x;
  res.y = acc.y / myden + b4.y;
  res.z = acc.z / myden + b4.z;
  res.w = acc.w / myden + b4.w;
  res.x = (res.x > 0.f) ? res.x : (__expf(res.x) - 1.f);
  res.y = (res.y > 0.f) ? res.y : (__expf(res.y) - 1.f);
  res.z = (res.z > 0.f) ? res.z : (__expf(res.z) - 1.f);
  res.w = (res.w > 0.f) ? res.w : (__expf(res.w) - 1.f);
  *(float4*)(out + (size_t)n * 256 + lane * 4) = res;
}

// ---------------- GAT layer-2 aggregation: 1 wave per node, H=1 ----------
__global__ __launch_bounds__(256) void gat_agg1_k(
    const int* __restrict__ offsets, const int* __restrict__ csr,
    const bf16* __restrict__ h, const float* __restrict__ as_,
    const float* __restrict__ ad_, const float* __restrict__ bias,
    float* __restrict__ out) {
  __shared__ float exs[4][64];
  __shared__ int srcs[4][64];
  int wv = threadIdx.x >> 6, lane = threadIdx.x & 63;
  int n = blockIdx.x * 4 + wv;
  int slot = lane >> 5, cp = lane & 31;
  int beg = offsets[n], end = offsets[n + 1];
  float adn = ad_[n];
  float m = -1e30f, den = 0.f;
  float ax = 0.f, ay = 0.f;
  for (int base = beg; base < end; base += 64) {
    int cnt = min(64, end - base);
    int src = 0;
    float l = -1e30f;
    if (lane < cnt) {
      src = csr[base + lane];
      float t = as_[src] + adn;
      l = (t > 0.f) ? t : NEG * t;
    }
    float mt = l;
#pragma unroll
    for (int off = 32; off; off >>= 1) mt = fmaxf(mt, __shfl_xor(mt, off));
    float M = fmaxf(m, mt);
    float ex = (lane < cnt) ? __expf(l - M) : 0.f;
    float s = ex;
#pragma unroll
    for (int off = 32; off; off >>= 1) s += __shfl_xor(s, off);
    float sc = __expf(m - M);
    den = den * sc + s;
    m = M;
    ax *= sc; ay *= sc;
    exs[wv][lane] = ex;
    srcs[wv][lane] = src;
    __builtin_amdgcn_wave_barrier();
    int e = 0;
    for (; e + 8 <= cnt; e += 8) {
      int i0 = e + slot, i1 = e + 2 + slot, i2 = e + 4 + slot, i3 = e + 6 + slot;
      int si0 = srcs[wv][i0], si1 = srcs[wv][i1], si2 = srcs[wv][i2], si3 = srcs[wv][i3];
      float w0 = exs[wv][i0], w1 = exs[wv][i1], w2 = exs[wv][i2], w3 = exs[wv][i3];
      ushort2 r0 = *(const ushort2*)(h + (size_t)si0 * 64 + cp * 2);
      ushort2 r1 = *(const ushort2*)(h + (size_t)si1 * 64 + cp * 2);
      ushort2 r2 = *(const ushort2*)(h + (size_t)si2 * 64 + cp * 2);
      ushort2 r3 = *(const ushort2*)(h + (size_t)si3 * 64 + cp * 2);
      ax += w0 * bf2f(r0.x); ay += w0 * bf2f(r0.y);
      ax += w1 * bf2f(r1.x); ay += w1 * bf2f(r1.y);
      ax += w2 * bf2f(r2.x); ay += w2 * bf2f(r2.y);
      ax += w3 * bf2f(r3.x); ay += w3 * bf2f(r3.y);
    }
    for (; e < cnt; e += 2) {
      int i = e + slot;
      int ok = (i < cnt);
      int si = srcs[wv][ok ? i : 0];
      float w = ok ? exs[wv][i] : 0.f;
      ushort2 r = *(const ushort2*)(h + (size_t)si * 64 + cp * 2);
      ax += w * bf2f(r.x); ay += w * bf2f(r.y);
    }
  }
  ax += __shfl_xor(ax, 32);
  ay += __shfl_xor(ay, 32);
  if (slot == 0) {
    float2 res;
    res.x = ax / den + bias[cp * 2];
    res.y = ay / den + bias[cp * 2 + 1];
    *(float2*)(out + (size_t)n * 64 + cp * 2) = res;
  }
}

// ---------------- fused edge MLP: 2 edges per wave ------------------------
__global__ __launch_bounds__(256) void edge_out_k(
    const int* __restrict__ ei, const bf16* __restrict__ pq,
    const float* __restrict__ mb1, const float* __restrict__ w2,
    const float* __restrict__ mb2, float* __restrict__ out) {
  int wid = blockIdx.x * 4 + (threadIdx.x >> 6);
  int lane = threadIdx.x & 63;
  int slot = lane >> 5, cp = lane & 31;
  int e = wid * 2 + slot;
  if (e >= NE) return;
  int s = ei[e], d = ei[NE + e];
  ushort2 rp = *(const ushort2*)(pq + (size_t)s * 128 + cp * 2);
  ushort2 rq = *(const ushort2*)(pq + (size_t)d * 128 + 64 + cp * 2);
  float2 mb = *(const float2*)(mb1 + cp * 2);
  float2 wv2 = *(const float2*)(w2 + cp * 2);
  float v0 = bf2f(rp.x) + bf2f(rq.x) + mb.x;
  float v1 = bf2f(rp.y) + bf2f(rq.y) + mb.y;
  v0 = fmaxf(v0, 0.f);
  v1 = fmaxf(v1, 0.f);
  float r = v0 * wv2.x + v1 * wv2.y;
#pragma unroll
  for (int off = 16; off; off >>= 1) r += __shfl_xor(r, off);
  if (cp == 0) out[e] = r + mb2[0];
}

extern "C" void kernel_launch(void* const* d_in, const int* in_sizes, int n_in,
                              void* d_out, int out_size, void* d_ws, size_t ws_size,
                              hipStream_t stream) {
  const float* x = (const float*)d_in[0];
  const int* ei = (const int*)d_in[1];
  const float* W1 = (const float*)d_in[2];
  const float* as1w = (const float*)d_in[3];
  const float* ad1w = (const float*)d_in[4];
  const float* b1 = (const float*)d_in[5];
  const float* W2 = (const float*)d_in[6];
  const float* as2w = (const float*)d_in[7];
  const float* ad2w = (const float*)d_in[8];
  const float* b2 = (const float*)d_in[9];
  const float* mw1 = (const float*)d_in[10];
  const float* mb1 = (const float*)d_in[11];
  const float* mw2 = (const float*)d_in[12];
  const float* mb2 = (const float*)d_in[13];
  float* out = (float*)d_out;

  char* ws = (char*)d_ws;
  size_t o = 0;
  auto alloc = [&](size_t bytes) {
    void* ptr = ws + o;
    o += (bytes + 255) & ~(size_t)255;
    return ptr;
  };
  int* counts = (int*)alloc((size_t)NN * 4);
  int* offsets = (int*)alloc((size_t)(NN + 1) * 4);
  int* cursor = (int*)alloc((size_t)NN * 4);
  int* bsums = (int*)alloc((size_t)NB * 4);
  int* csr = (int*)alloc((size_t)ET * 4);
  bf16* h1b = (bf16*)alloc((size_t)NN * 256 * 2);   // reused: h2b / pq
  float* a_s1 = (float*)alloc((size_t)NN * 4 * 4);
  float* a_d1 = (float*)alloc((size_t)NN * 4 * 4);
  float* x2 = (float*)alloc((size_t)NN * 256 * 4);
  float* y = (float*)alloc((size_t)NN * 64 * 4);
  bf16* h2b = h1b;                        // NN*64 bf16
  bf16* pq = h1b + (size_t)NN * 64;       // NN*128 bf16, interleaved [p|q]

  // CSR build (shared by both GAT layers; includes self loops)
  zero_counts_k<<<NB, 256, 0, stream>>>(counts);
  hist_k<<<(ET + 255) / 256, 256, 0, stream>>>(ei, counts);
  scan_bsum_k<<<NB, 256, 0, stream>>>(counts, bsums);
  scan_top_k<<<1, 256, 0, stream>>>(bsums);
  scan_final_k<<<NB, 256, 0, stream>>>(counts, bsums, offsets, cursor);
  scatter_k<<<(ET + 255) / 256, 256, 0, stream>>>(ei, cursor, csr);

  // Layer 1: h1 = x @ W1 (bf16) + fused attention dots; aggregate -> x2
  gemm_k<bf16, 1><<<dim3(4, (NN + 63) / 64), 256, 0, stream>>>(
      x, W1, h1b, NN, 256, 128, 256, 0, as1w, ad1w, a_s1, a_d1, 4);
  gat_agg4_k<<<NN / 4, 256, 0, stream>>>(offsets, csr, h1b, a_s1, a_d1, b1, x2);

  // Layer 2: h2 = x2 @ W2 (bf16) + fused dots; aggregate -> y
  gemm_k<bf16, 1><<<dim3(1, (NN + 63) / 64), 256, 0, stream>>>(
      x2, W2, h2b, NN, 64, 256, 64, 0, as2w, ad2w, a_s1, a_d1, 1);
  gat_agg1_k<<<NN / 4, 256, 0, stream>>>(offsets, csr, h2b, a_s1, a_d1, b2, y);

  // Edge MLP decomposition: pq[:, :64] = y @ mw1[:64], pq[:, 64:] = y @ mw1[64:]
  gemm_k<bf16, 0><<<dim3(1, (NN + 63) / 64), 256, 0, stream>>>(
      y, mw1, pq, NN, 64, 64, 128, 0, nullptr, nullptr, nullptr, nullptr, 0);
  gemm_k<bf16, 0><<<dim3(1, (NN + 63) / 64), 256, 0, stream>>>(
      y, mw1 + 64 * 64, pq, NN, 64, 64, 128, 64, nullptr, nullptr, nullptr, nullptr, 0);

  // Final per-edge output
  edge_out_k<<<(NE / 2 + 3) / 4, 256, 0, stream>>>(ei, pq, mb1, mw2, mb2, out);
}

// Round 5
// 327.077 us; speedup vs baseline: 2.3324x; 1.2583x over previous
//
#include <hip/hip_runtime.h>
#include <hip/hip_bf16.h>
#include <math.h>

#define NN 50000
#define NE 800000
#define ET (NE + NN)
#define NB ((NN + 255) / 256)
#define NEG 0.2f

typedef __hip_bfloat16 bf16;
typedef __attribute__((ext_vector_type(8))) short s8v;
typedef __attribute__((ext_vector_type(4))) float f4v;

__device__ __forceinline__ float bf2f(unsigned short u) {
  union { unsigned int i; float f; } c;
  c.i = ((unsigned int)u) << 16;
  return c.f;
}
__device__ __forceinline__ unsigned short f2b(float f) {
  bf16 b = __float2bfloat16(f);
  return __builtin_bit_cast(unsigned short, b);
}

// ---------------- CSR build ----------------
__global__ void zero_counts_k(int* __restrict__ c) {
  int i = blockIdx.x * 256 + threadIdx.x;
  if (i < NN) c[i] = 0;
}

__global__ void hist_k(const int* __restrict__ ei, int* __restrict__ counts) {
  int e = blockIdx.x * 256 + threadIdx.x;
  if (e >= ET) return;
  int d = (e < NE) ? ei[NE + e] : (e - NE);
  atomicAdd(&counts[d], 1);
}

__global__ __launch_bounds__(256) void scan_bsum_k(const int* __restrict__ counts,
                                                   int* __restrict__ bsums) {
  __shared__ int wsum[4];
  int i = blockIdx.x * 256 + threadIdx.x;
  int v = (i < NN) ? counts[i] : 0;
#pragma unroll
  for (int off = 32; off; off >>= 1) v += __shfl_xor(v, off);
  if ((threadIdx.x & 63) == 0) wsum[threadIdx.x >> 6] = v;
  __syncthreads();
  if (threadIdx.x == 0) bsums[blockIdx.x] = wsum[0] + wsum[1] + wsum[2] + wsum[3];
}

__global__ __launch_bounds__(256) void scan_top_k(int* __restrict__ bsums) {
  __shared__ int s[256];
  int t = threadIdx.x;
  int v = (t < NB) ? bsums[t] : 0;
  s[t] = v;
  __syncthreads();
  for (int off = 1; off < 256; off <<= 1) {
    int u = (t >= off) ? s[t - off] : 0;
    __syncthreads();
    s[t] += u;
    __syncthreads();
  }
  if (t < NB) bsums[t] = s[t] - v;  // exclusive
}

__global__ __launch_bounds__(256) void scan_final_k(const int* __restrict__ counts,
                                                    const int* __restrict__ bsums,
                                                    int* __restrict__ offsets,
                                                    int* __restrict__ cursor) {
  __shared__ int s[256];
  int t = threadIdx.x;
  int i = blockIdx.x * 256 + t;
  int v = (i < NN) ? counts[i] : 0;
  s[t] = v;
  __syncthreads();
  for (int off = 1; off < 256; off <<= 1) {
    int u = (t >= off) ? s[t - off] : 0;
    __syncthreads();
    s[t] += u;
    __syncthreads();
  }
  int excl = s[t] - v + bsums[blockIdx.x];
  if (i < NN) {
    offsets[i] = excl;
    cursor[i] = excl;
    if (i == NN - 1) offsets[NN] = excl + v;
  }
}

__global__ void scatter_k(const int* __restrict__ ei, int* __restrict__ cursor,
                          int* __restrict__ csr) {
  int e = blockIdx.x * 256 + threadIdx.x;
  if (e >= ET) return;
  int s, d;
  if (e < NE) { s = ei[e]; d = ei[NE + e]; } else { s = e - NE; d = s; }
  int pos = atomicAdd(&cursor[d], 1);
  csr[pos] = s;
}

// ---------------- fp32 -> bf16 conversions ----------------
__global__ void convx_k(const float* __restrict__ in, unsigned short* __restrict__ out,
                        int n4) {
  int i = blockIdx.x * 256 + threadIdx.x;
  if (i >= n4) return;
  float4 v = *(const float4*)(in + (size_t)i * 4);
  ushort4 o = {f2b(v.x), f2b(v.y), f2b(v.z), f2b(v.w)};
  *(ushort4*)(out + (size_t)i * 4) = o;
}

// out[n*K+k] = in[k*N+n]  (transpose + cast)
__global__ void convT_k(const float* __restrict__ in, unsigned short* __restrict__ out,
                        int K, int N) {
  int i = blockIdx.x * 256 + threadIdx.x;
  if (i >= K * N) return;
  int n = i / K, k = i - n * K;
  out[i] = f2b(in[(size_t)k * N + n]);
}

// pqT[n][k] (n<64: p-weights mw1[k][n]; n>=64: q-weights mw1[64+k][n-64]), K=64
__global__ void convPQ_k(const float* __restrict__ mw1, unsigned short* __restrict__ out) {
  int i = blockIdx.x * 256 + threadIdx.x;
  if (i >= 128 * 64) return;
  int n = i >> 6, k = i & 63;
  float v = (n < 64) ? mw1[(size_t)k * 64 + n] : mw1[(size_t)(64 + k) * 64 + (n - 64)];
  out[i] = f2b(v);
}

// ---------------- bf16 MFMA GEMM: C[M,N] = A[M,K] @ Bt[N,K]^T ----------------
// 64x64 tile, 4 waves (2x2), each wave 32x32 via 2x2 mfma_f32_16x16x32_bf16.
// DOTS: fused attention dots from fp32 acc (head = blockIdx.x, BN==64==head).
template <int DOTS>
__global__ __launch_bounds__(256) void mgemm_k(
    const unsigned short* __restrict__ A, int lda,
    const unsigned short* __restrict__ Bt, int ldb,
    unsigned short* __restrict__ C, int ldc,
    int M, int N, int K,
    const float* __restrict__ ws, const float* __restrict__ wd,
    float* __restrict__ as_, float* __restrict__ ad_, int H) {
  __shared__ unsigned short Asl[64][40];   // +8 pad: row stride 80B = 20 banks
  __shared__ unsigned short Btl[64][40];
  __shared__ float sdot[64], ddot[64];
  int bm = blockIdx.y * 64, bn = blockIdx.x * 64;
  int t = threadIdx.x;
  int wv = t >> 6, lane = t & 63;
  int wm = (wv >> 1) * 32, wn = (wv & 1) * 32;
  int l16 = lane & 15, lq = lane >> 4;
  if (DOTS && t < 64) { sdot[t] = 0.f; ddot[t] = 0.f; }
  f4v acc[2][2];
#pragma unroll
  for (int mi = 0; mi < 2; ++mi)
#pragma unroll
    for (int ni = 0; ni < 2; ++ni) {
      acc[mi][ni][0] = 0.f; acc[mi][ni][1] = 0.f;
      acc[mi][ni][2] = 0.f; acc[mi][ni][3] = 0.f;
    }
  int sr = t >> 2, sc = (t & 3) * 8;  // 4 threads/row, 8 bf16 (16B) each
  for (int k0 = 0; k0 < K; k0 += 32) {
    uint4 av = {0, 0, 0, 0};
    int gr = bm + sr;
    if (gr < M) av = *(const uint4*)(A + (size_t)gr * lda + k0 + sc);
    *(uint4*)&Asl[sr][sc] = av;
    uint4 bv = *(const uint4*)(Bt + (size_t)(bn + sr) * ldb + k0 + sc);
    *(uint4*)&Btl[sr][sc] = bv;
    __syncthreads();
    s8v af[2], bfv[2];
#pragma unroll
    for (int mi = 0; mi < 2; ++mi)
      af[mi] = *(const s8v*)&Asl[wm + mi * 16 + l16][lq * 8];
#pragma unroll
    for (int ni = 0; ni < 2; ++ni)
      bfv[ni] = *(const s8v*)&Btl[wn + ni * 16 + l16][lq * 8];
#pragma unroll
    for (int mi = 0; mi < 2; ++mi)
#pragma unroll
      for (int ni = 0; ni < 2; ++ni)
        acc[mi][ni] = __builtin_amdgcn_mfma_f32_16x16x32_bf16(
            af[mi], bfv[ni], acc[mi][ni], 0, 0, 0);
    __syncthreads();
  }
  // C store: D row = (lane>>4)*4 + reg, col = lane&15 (m89-verified layout)
#pragma unroll
  for (int mi = 0; mi < 2; ++mi)
#pragma unroll
    for (int rr = 0; rr < 4; ++rr) {
      int row = bm + wm + mi * 16 + lq * 4 + rr;
      if (row < M) {
#pragma unroll
        for (int ni = 0; ni < 2; ++ni) {
          int col = bn + wn + ni * 16 + l16;
          C[(size_t)row * ldc + col] = f2b(acc[mi][ni][rr]);
        }
      }
    }
  if (DOTS) {
    int head = blockIdx.x;
    float ps[2][4], pd[2][4];
#pragma unroll
    for (int mi = 0; mi < 2; ++mi)
#pragma unroll
      for (int rr = 0; rr < 4; ++rr) {
        float s = 0.f, d = 0.f;
#pragma unroll
        for (int ni = 0; ni < 2; ++ni) {
          int col = wn + ni * 16 + l16;
          s += acc[mi][ni][rr] * ws[head * 64 + col];
          d += acc[mi][ni][rr] * wd[head * 64 + col];
        }
        ps[mi][rr] = s;
        pd[mi][rr] = d;
      }
#pragma unroll
    for (int off = 1; off < 16; off <<= 1)
#pragma unroll
      for (int mi = 0; mi < 2; ++mi)
#pragma unroll
        for (int rr = 0; rr < 4; ++rr) {
          ps[mi][rr] += __shfl_xor(ps[mi][rr], off);
          pd[mi][rr] += __shfl_xor(pd[mi][rr], off);
        }
    if (l16 == 0) {
#pragma unroll
      for (int mi = 0; mi < 2; ++mi)
#pragma unroll
        for (int rr = 0; rr < 4; ++rr) {
          int rl = wm + mi * 16 + lq * 4 + rr;
          atomicAdd(&sdot[rl], ps[mi][rr]);
          atomicAdd(&ddot[rl], pd[mi][rr]);
        }
    }
    __syncthreads();
    if (t < 64 && bm + t < M) {
      as_[(size_t)(bm + t) * H + head] = sdot[t];
      ad_[(size_t)(bm + t) * H + head] = ddot[t];
    }
  }
}

// ---------------- GAT layer-1 aggregation: 1 wave per node, 4 heads -------
__global__ __launch_bounds__(256) void gat_agg4_k(
    const int* __restrict__ offsets, const int* __restrict__ csr,
    const unsigned short* __restrict__ h, const float* __restrict__ as_,
    const float* __restrict__ ad_, const float* __restrict__ bias,
    unsigned short* __restrict__ out) {
  __shared__ float exs[4][64][4];
  __shared__ int srcs[4][64];
  int wv = threadIdx.x >> 6, lane = threadIdx.x & 63;
  int n = blockIdx.x * 4 + wv;
  int hd = lane >> 4;
  int beg = offsets[n], end = offsets[n + 1];
  float4 adn = *(const float4*)(ad_ + (size_t)n * 4);
  float m0 = -1e30f, m1 = -1e30f, m2 = -1e30f, m3 = -1e30f;
  float d0 = 0.f, d1 = 0.f, d2 = 0.f, d3 = 0.f;
  float4 acc = {0.f, 0.f, 0.f, 0.f};
  for (int base = beg; base < end; base += 64) {
    int cnt = min(64, end - base);
    int src = 0;
    float l0 = -1e30f, l1 = -1e30f, l2 = -1e30f, l3 = -1e30f;
    if (lane < cnt) {
      src = csr[base + lane];
      float4 a4 = *(const float4*)(as_ + (size_t)src * 4);
      float t;
      t = a4.x + adn.x; l0 = (t > 0.f) ? t : NEG * t;
      t = a4.y + adn.y; l1 = (t > 0.f) ? t : NEG * t;
      t = a4.z + adn.z; l2 = (t > 0.f) ? t : NEG * t;
      t = a4.w + adn.w; l3 = (t > 0.f) ? t : NEG * t;
    }
    float t0 = l0, t1 = l1, t2 = l2, t3 = l3;
#pragma unroll
    for (int off = 32; off; off >>= 1) {
      t0 = fmaxf(t0, __shfl_xor(t0, off));
      t1 = fmaxf(t1, __shfl_xor(t1, off));
      t2 = fmaxf(t2, __shfl_xor(t2, off));
      t3 = fmaxf(t3, __shfl_xor(t3, off));
    }
    float M0 = fmaxf(m0, t0), M1 = fmaxf(m1, t1), M2 = fmaxf(m2, t2), M3 = fmaxf(m3, t3);
    float e0 = 0.f, e1 = 0.f, e2 = 0.f, e3 = 0.f;
    if (lane < cnt) {
      e0 = __expf(l0 - M0); e1 = __expf(l1 - M1);
      e2 = __expf(l2 - M2); e3 = __expf(l3 - M3);
    }
    float s0 = e0, s1 = e1, s2 = e2, s3 = e3;
#pragma unroll
    for (int off = 32; off; off >>= 1) {
      s0 += __shfl_xor(s0, off);
      s1 += __shfl_xor(s1, off);
      s2 += __shfl_xor(s2, off);
      s3 += __shfl_xor(s3, off);
    }
    float sc0 = __expf(m0 - M0), sc1 = __expf(m1 - M1);
    float sc2 = __expf(m2 - M2), sc3 = __expf(m3 - M3);
    d0 = d0 * sc0 + s0; d1 = d1 * sc1 + s1;
    d2 = d2 * sc2 + s2; d3 = d3 * sc3 + s3;
    m0 = M0; m1 = M1; m2 = M2; m3 = M3;
    float mysc = (hd == 0) ? sc0 : (hd == 1) ? sc1 : (hd == 2) ? sc2 : sc3;
    acc.x *= mysc; acc.y *= mysc; acc.z *= mysc; acc.w *= mysc;
    float4 ex4 = {e0, e1, e2, e3};
    *(float4*)(&exs[wv][lane][0]) = ex4;
    srcs[wv][lane] = src;
    __builtin_amdgcn_wave_barrier();
    int e = 0;
    for (; e + 4 <= cnt; e += 4) {
      int si0 = srcs[wv][e], si1 = srcs[wv][e + 1];
      int si2 = srcs[wv][e + 2], si3 = srcs[wv][e + 3];
      float w0 = exs[wv][e][hd], w1 = exs[wv][e + 1][hd];
      float w2 = exs[wv][e + 2][hd], w3 = exs[wv][e + 3][hd];
      ushort4 r0 = *(const ushort4*)(h + (size_t)si0 * 256 + lane * 4);
      ushort4 r1 = *(const ushort4*)(h + (size_t)si1 * 256 + lane * 4);
      ushort4 r2 = *(const ushort4*)(h + (size_t)si2 * 256 + lane * 4);
      ushort4 r3 = *(const ushort4*)(h + (size_t)si3 * 256 + lane * 4);
      acc.x += w0 * bf2f(r0.x); acc.y += w0 * bf2f(r0.y);
      acc.z += w0 * bf2f(r0.z); acc.w += w0 * bf2f(r0.w);
      acc.x += w1 * bf2f(r1.x); acc.y += w1 * bf2f(r1.y);
      acc.z += w1 * bf2f(r1.z); acc.w += w1 * bf2f(r1.w);
      acc.x += w2 * bf2f(r2.x); acc.y += w2 * bf2f(r2.y);
      acc.z += w2 * bf2f(r2.z); acc.w += w2 * bf2f(r2.w);
      acc.x += w3 * bf2f(r3.x); acc.y += w3 * bf2f(r3.y);
      acc.z += w3 * bf2f(r3.z); acc.w += w3 * bf2f(r3.w);
    }
    for (; e < cnt; ++e) {
      int si = srcs[wv][e];
      float w = exs[wv][e][hd];
      ushort4 r = *(const ushort4*)(h + (size_t)si * 256 + lane * 4);
      acc.x += w * bf2f(r.x); acc.y += w * bf2f(r.y);
      acc.z += w * bf2f(r.z); acc.w += w * bf2f(r.w);
    }
  }
  float myden = (hd == 0) ? d0 : (hd == 1) ? d1 : (hd == 2) ? d2 : d3;
  float4 b4 = *(const float4*)(bias + lane * 4);
  float4 res;
  res.x = acc.x / myden + b4.x;
  res.y = acc.y / myden + b4.y;
  res.z = acc.z / myden + b4.z;
  res.w = acc.w / myden + b4.w;
  res.x = (res.x > 0.f) ? res.x : (__expf(res.x) - 1.f);
  res.y = (res.y > 0.f) ? res.y : (__expf(res.y) - 1.f);
  res.z = (res.z > 0.f) ? res.z : (__expf(res.z) - 1.f);
  res.w = (res.w > 0.f) ? res.w : (__expf(res.w) - 1.f);
  ushort4 ov = {f2b(res.x), f2b(res.y), f2b(res.z), f2b(res.w)};
  *(ushort4*)(out + (size_t)n * 256 + lane * 4) = ov;
}

// ---------------- GAT layer-2 aggregation: 1 wave per node, H=1 ----------
__global__ __launch_bounds__(256) void gat_agg1_k(
    const int* __restrict__ offsets, const int* __restrict__ csr,
    const unsigned short* __restrict__ h, const float* __restrict__ as_,
    const float* __restrict__ ad_, const float* __restrict__ bias,
    unsigned short* __restrict__ out) {
  __shared__ float exs[4][64];
  __shared__ int srcs[4][64];
  int wv = threadIdx.x >> 6, lane = threadIdx.x & 63;
  int n = blockIdx.x * 4 + wv;
  int slot = lane >> 5, cp = lane & 31;
  int beg = offsets[n], end = offsets[n + 1];
  float adn = ad_[n];
  float m = -1e30f, den = 0.f;
  float ax = 0.f, ay = 0.f;
  for (int base = beg; base < end; base += 64) {
    int cnt = min(64, end - base);
    int src = 0;
    float l = -1e30f;
    if (lane < cnt) {
      src = csr[base + lane];
      float t = as_[src] + adn;
      l = (t > 0.f) ? t : NEG * t;
    }
    float mt = l;
#pragma unroll
    for (int off = 32; off; off >>= 1) mt = fmaxf(mt, __shfl_xor(mt, off));
    float M = fmaxf(m, mt);
    float ex = (lane < cnt) ? __expf(l - M) : 0.f;
    float s = ex;
#pragma unroll
    for (int off = 32; off; off >>= 1) s += __shfl_xor(s, off);
    float sc = __expf(m - M);
    den = den * sc + s;
    m = M;
    ax *= sc; ay *= sc;
    exs[wv][lane] = ex;
    srcs[wv][lane] = src;
    __builtin_amdgcn_wave_barrier();
    int e = 0;
    for (; e + 8 <= cnt; e += 8) {
      int i0 = e + slot, i1 = e + 2 + slot, i2 = e + 4 + slot, i3 = e + 6 + slot;
      int si0 = srcs[wv][i0], si1 = srcs[wv][i1], si2 = srcs[wv][i2], si3 = srcs[wv][i3];
      float w0 = exs[wv][i0], w1 = exs[wv][i1], w2 = exs[wv][i2], w3 = exs[wv][i3];
      ushort2 r0 = *(const ushort2*)(h + (size_t)si0 * 64 + cp * 2);
      ushort2 r1 = *(const ushort2*)(h + (size_t)si1 * 64 + cp * 2);
      ushort2 r2 = *(const ushort2*)(h + (size_t)si2 * 64 + cp * 2);
      ushort2 r3 = *(const ushort2*)(h + (size_t)si3 * 64 + cp * 2);
      ax += w0 * bf2f(r0.x); ay += w0 * bf2f(r0.y);
      ax += w1 * bf2f(r1.x); ay += w1 * bf2f(r1.y);
      ax += w2 * bf2f(r2.x); ay += w2 * bf2f(r2.y);
      ax += w3 * bf2f(r3.x); ay += w3 * bf2f(r3.y);
    }
    for (; e < cnt; e += 2) {
      int i = e + slot;
      int ok = (i < cnt);
      int si = srcs[wv][ok ? i : 0];
      float w = ok ? exs[wv][i] : 0.f;
      ushort2 r = *(const ushort2*)(h + (size_t)si * 64 + cp * 2);
      ax += w * bf2f(r.x); ay += w * bf2f(r.y);
    }
  }
  ax += __shfl_xor(ax, 32);
  ay += __shfl_xor(ay, 32);
  if (slot == 0) {
    ushort2 ov;
    ov.x = f2b(ax / den + bias[cp * 2]);
    ov.y = f2b(ay / den + bias[cp * 2 + 1]);
    *(ushort2*)(out + (size_t)n * 64 + cp * 2) = ov;
  }
}

// ---------------- fused edge MLP: 2 edges per wave ------------------------
__global__ __launch_bounds__(256) void edge_out_k(
    const int* __restrict__ ei, const unsigned short* __restrict__ pq,
    const float* __restrict__ mb1, const float* __restrict__ w2,
    const float* __restrict__ mb2, float* __restrict__ out) {
  int wid = blockIdx.x * 4 + (threadIdx.x >> 6);
  int lane = threadIdx.x & 63;
  int slot = lane >> 5, cp = lane & 31;
  int e = wid * 2 + slot;
  if (e >= NE) return;
  int s = ei[e], d = ei[NE + e];
  ushort2 rp = *(const ushort2*)(pq + (size_t)s * 128 + cp * 2);
  ushort2 rq = *(const ushort2*)(pq + (size_t)d * 128 + 64 + cp * 2);
  float2 mb = *(const float2*)(mb1 + cp * 2);
  float2 wv2 = *(const float2*)(w2 + cp * 2);
  float v0 = bf2f(rp.x) + bf2f(rq.x) + mb.x;
  float v1 = bf2f(rp.y) + bf2f(rq.y) + mb.y;
  v0 = fmaxf(v0, 0.f);
  v1 = fmaxf(v1, 0.f);
  float r = v0 * wv2.x + v1 * wv2.y;
#pragma unroll
  for (int off = 16; off; off >>= 1) r += __shfl_xor(r, off);
  if (cp == 0) out[e] = r + mb2[0];
}

extern "C" void kernel_launch(void* const* d_in, const int* in_sizes, int n_in,
                              void* d_out, int out_size, void* d_ws, size_t ws_size,
                              hipStream_t stream) {
  const float* x = (const float*)d_in[0];
  const int* ei = (const int*)d_in[1];
  const float* W1 = (const float*)d_in[2];
  const float* as1w = (const float*)d_in[3];
  const float* ad1w = (const float*)d_in[4];
  const float* b1 = (const float*)d_in[5];
  const float* W2 = (const float*)d_in[6];
  const float* as2w = (const float*)d_in[7];
  const float* ad2w = (const float*)d_in[8];
  const float* b2 = (const float*)d_in[9];
  const float* mw1 = (const float*)d_in[10];
  const float* mb1 = (const float*)d_in[11];
  const float* mw2 = (const float*)d_in[12];
  const float* mb2 = (const float*)d_in[13];
  float* out = (float*)d_out;

  char* ws = (char*)d_ws;
  size_t o = 0;
  auto alloc = [&](size_t bytes) {
    void* ptr = ws + o;
    o += (bytes + 255) & ~(size_t)255;
    return ptr;
  };
  int* counts = (int*)alloc((size_t)NN * 4);
  int* offsets = (int*)alloc((size_t)(NN + 1) * 4);
  int* cursor = (int*)alloc((size_t)NN * 4);
  int* bsums = (int*)alloc((size_t)NB * 4);
  int* csr = (int*)alloc((size_t)ET * 4);
  unsigned short* xb = (unsigned short*)alloc((size_t)NN * 128 * 2);
  unsigned short* w1t = (unsigned short*)alloc((size_t)256 * 128 * 2);
  unsigned short* w2t = (unsigned short*)alloc((size_t)64 * 256 * 2);
  unsigned short* pqt = (unsigned short*)alloc((size_t)128 * 64 * 2);
  unsigned short* h1b = (unsigned short*)alloc((size_t)NN * 256 * 2);  // reused h2b/pq
  float* a_s1 = (float*)alloc((size_t)NN * 4 * 4);
  float* a_d1 = (float*)alloc((size_t)NN * 4 * 4);
  unsigned short* x2b = (unsigned short*)alloc((size_t)NN * 256 * 2);
  unsigned short* yb = (unsigned short*)alloc((size_t)NN * 64 * 2);
  unsigned short* h2b = h1b;                  // NN*64
  unsigned short* pq = h1b + (size_t)NN * 64; // NN*128, [p|q]

  // CSR build (shared by both GAT layers; includes self loops)
  zero_counts_k<<<NB, 256, 0, stream>>>(counts);
  hist_k<<<(ET + 255) / 256, 256, 0, stream>>>(ei, counts);
  scan_bsum_k<<<NB, 256, 0, stream>>>(counts, bsums);
  scan_top_k<<<1, 256, 0, stream>>>(bsums);
  scan_final_k<<<NB, 256, 0, stream>>>(counts, bsums, offsets, cursor);
  scatter_k<<<(ET + 255) / 256, 256, 0, stream>>>(ei, cursor, csr);

  // Conversions: x -> bf16; weights -> transposed bf16
  convx_k<<<(NN * 32 + 255) / 256, 256, 0, stream>>>(x, xb, NN * 32);
  convT_k<<<(256 * 128 + 255) / 256, 256, 0, stream>>>(W1, w1t, 128, 256);
  convT_k<<<(64 * 256 + 255) / 256, 256, 0, stream>>>(W2, w2t, 256, 64);
  convPQ_k<<<(128 * 64 + 255) / 256, 256, 0, stream>>>(mw1, pqt);

  int gy = (NN + 63) / 64;
  // Layer 1: h1 = x @ W1 (MFMA, bf16) + fused dots; aggregate -> x2 (bf16)
  mgemm_k<1><<<dim3(4, gy), 256, 0, stream>>>(xb, 128, w1t, 128, h1b, 256,
                                              NN, 256, 128, as1w, ad1w, a_s1, a_d1, 4);
  gat_agg4_k<<<NN / 4, 256, 0, stream>>>(offsets, csr, h1b, a_s1, a_d1, b1, x2b);

  // Layer 2: h2 = x2 @ W2 (MFMA) + fused dots; aggregate -> y (bf16)
  mgemm_k<1><<<dim3(1, gy), 256, 0, stream>>>(x2b, 256, w2t, 256, h2b, 64,
                                              NN, 64, 256, as2w, ad2w, a_s1, a_d1, 1);
  gat_agg1_k<<<NN / 4, 256, 0, stream>>>(offsets, csr, h2b, a_s1, a_d1, b2, yb);

  // Edge MLP: pq = y @ [mw1[:64] | mw1[64:]]  (one MFMA GEMM, N=128)
  mgemm_k<0><<<dim3(2, gy), 256, 0, stream>>>(yb, 64, pqt, 64, pq, 128,
                                              NN, 128, 64, nullptr, nullptr,
                                              nullptr, nullptr, 0);

  // Final per-edge output
  edge_out_k<<<(NE / 2 + 3) / 4, 256, 0, stream>>>(ei, pq, mb1, mw2, mb2, out);
}

// Round 6
// 307.193 us; speedup vs baseline: 2.4833x; 1.0647x over previous
//
#include <hip/hip_runtime.h>
#include <hip/hip_bf16.h>
#include <math.h>

#define NN 50000
#define NE 800000
#define ET (NE + NN)
#define NB ((NN + 255) / 256)
#define NEG 0.2f

typedef __hip_bfloat16 bf16;
typedef __attribute__((ext_vector_type(8))) short s8v;
typedef __attribute__((ext_vector_type(4))) float f4v;

__device__ __forceinline__ float bf2f(unsigned short u) {
  union { unsigned int i; float f; } c;
  c.i = ((unsigned int)u) << 16;
  return c.f;
}
__device__ __forceinline__ unsigned short f2b(float f) {
  bf16 b = __float2bfloat16(f);
  return __builtin_bit_cast(unsigned short, b);
}

// ---------------- CSR build (payload: {src, edge_id or -1}) ----------------
__global__ void zero_counts_k(int* __restrict__ c) {
  int i = blockIdx.x * 256 + threadIdx.x;
  if (i < NN) c[i] = 0;
}

__global__ void hist_k(const int* __restrict__ ei, int* __restrict__ counts) {
  int e = blockIdx.x * 256 + threadIdx.x;
  if (e >= ET) return;
  int d = (e < NE) ? ei[NE + e] : (e - NE);
  atomicAdd(&counts[d], 1);
}

__global__ __launch_bounds__(256) void scan_bsum_k(const int* __restrict__ counts,
                                                   int* __restrict__ bsums) {
  __shared__ int wsum[4];
  int i = blockIdx.x * 256 + threadIdx.x;
  int v = (i < NN) ? counts[i] : 0;
#pragma unroll
  for (int off = 32; off; off >>= 1) v += __shfl_xor(v, off);
  if ((threadIdx.x & 63) == 0) wsum[threadIdx.x >> 6] = v;
  __syncthreads();
  if (threadIdx.x == 0) bsums[blockIdx.x] = wsum[0] + wsum[1] + wsum[2] + wsum[3];
}

__global__ __launch_bounds__(256) void scan_top_k(int* __restrict__ bsums) {
  __shared__ int s[256];
  int t = threadIdx.x;
  int v = (t < NB) ? bsums[t] : 0;
  s[t] = v;
  __syncthreads();
  for (int off = 1; off < 256; off <<= 1) {
    int u = (t >= off) ? s[t - off] : 0;
    __syncthreads();
    s[t] += u;
    __syncthreads();
  }
  if (t < NB) bsums[t] = s[t] - v;  // exclusive
}

__global__ __launch_bounds__(256) void scan_final_k(const int* __restrict__ counts,
                                                    const int* __restrict__ bsums,
                                                    int* __restrict__ offsets,
                                                    int* __restrict__ cursor) {
  __shared__ int s[256];
  int t = threadIdx.x;
  int i = blockIdx.x * 256 + t;
  int v = (i < NN) ? counts[i] : 0;
  s[t] = v;
  __syncthreads();
  for (int off = 1; off < 256; off <<= 1) {
    int u = (t >= off) ? s[t - off] : 0;
    __syncthreads();
    s[t] += u;
    __syncthreads();
  }
  int excl = s[t] - v + bsums[blockIdx.x];
  if (i < NN) {
    offsets[i] = excl;
    cursor[i] = excl;
    if (i == NN - 1) offsets[NN] = excl + v;
  }
}

__global__ void scatter_k(const int* __restrict__ ei, int* __restrict__ cursor,
                          int2* __restrict__ csr) {
  int e = blockIdx.x * 256 + threadIdx.x;
  if (e >= ET) return;
  int s, d, id;
  if (e < NE) { s = ei[e]; d = ei[NE + e]; id = e; }
  else { s = e - NE; d = s; id = -1; }
  int pos = atomicAdd(&cursor[d], 1);
  csr[pos] = make_int2(s, id);
}

// ---------------- fp32 -> bf16 conversions ----------------
__global__ void convx_k(const float* __restrict__ in, unsigned short* __restrict__ out,
                        int n4) {
  int i = blockIdx.x * 256 + threadIdx.x;
  if (i >= n4) return;
  float4 v = *(const float4*)(in + (size_t)i * 4);
  ushort4 o = {f2b(v.x), f2b(v.y), f2b(v.z), f2b(v.w)};
  *(ushort4*)(out + (size_t)i * 4) = o;
}

// out[n*K+k] = in[k*N+n]  (transpose + cast)
__global__ void convT_k(const float* __restrict__ in, unsigned short* __restrict__ out,
                        int K, int N) {
  int i = blockIdx.x * 256 + threadIdx.x;
  if (i >= K * N) return;
  int n = i / K, k = i - n * K;
  out[i] = f2b(in[(size_t)k * N + n]);
}

// pqT[n][k] (n<64: p-weights mw1[k][n]; n>=64: q-weights mw1[64+k][n-64]), K=64
__global__ void convPQ_k(const float* __restrict__ mw1, unsigned short* __restrict__ out) {
  int i = blockIdx.x * 256 + threadIdx.x;
  if (i >= 128 * 64) return;
  int n = i >> 6, k = i & 63;
  float v = (n < 64) ? mw1[(size_t)k * 64 + n] : mw1[(size_t)(64 + k) * 64 + (n - 64)];
  out[i] = f2b(v);
}

// ---------------- bf16 MFMA GEMM: C[M,N] = A[M,K] @ Bt[N,K]^T ----------------
template <int DOTS>
__global__ __launch_bounds__(256) void mgemm_k(
    const unsigned short* __restrict__ A, int lda,
    const unsigned short* __restrict__ Bt, int ldb,
    unsigned short* __restrict__ C, int ldc,
    int M, int N, int K,
    const float* __restrict__ ws, const float* __restrict__ wd,
    float* __restrict__ as_, float* __restrict__ ad_, int H) {
  __shared__ unsigned short Asl[64][40];   // +8 pad: row stride 80B = 20 banks
  __shared__ unsigned short Btl[64][40];
  __shared__ float sdot[64], ddot[64];
  int bm = blockIdx.y * 64, bn = blockIdx.x * 64;
  int t = threadIdx.x;
  int wv = t >> 6, lane = t & 63;
  int wm = (wv >> 1) * 32, wn = (wv & 1) * 32;
  int l16 = lane & 15, lq = lane >> 4;
  if (DOTS && t < 64) { sdot[t] = 0.f; ddot[t] = 0.f; }
  f4v acc[2][2];
#pragma unroll
  for (int mi = 0; mi < 2; ++mi)
#pragma unroll
    for (int ni = 0; ni < 2; ++ni) {
      acc[mi][ni][0] = 0.f; acc[mi][ni][1] = 0.f;
      acc[mi][ni][2] = 0.f; acc[mi][ni][3] = 0.f;
    }
  int sr = t >> 2, sc = (t & 3) * 8;  // 4 threads/row, 8 bf16 (16B) each
  for (int k0 = 0; k0 < K; k0 += 32) {
    uint4 av = {0, 0, 0, 0};
    int gr = bm + sr;
    if (gr < M) av = *(const uint4*)(A + (size_t)gr * lda + k0 + sc);
    *(uint4*)&Asl[sr][sc] = av;
    uint4 bv = *(const uint4*)(Bt + (size_t)(bn + sr) * ldb + k0 + sc);
    *(uint4*)&Btl[sr][sc] = bv;
    __syncthreads();
    s8v af[2], bfv[2];
#pragma unroll
    for (int mi = 0; mi < 2; ++mi)
      af[mi] = *(const s8v*)&Asl[wm + mi * 16 + l16][lq * 8];
#pragma unroll
    for (int ni = 0; ni < 2; ++ni)
      bfv[ni] = *(const s8v*)&Btl[wn + ni * 16 + l16][lq * 8];
#pragma unroll
    for (int mi = 0; mi < 2; ++mi)
#pragma unroll
      for (int ni = 0; ni < 2; ++ni)
        acc[mi][ni] = __builtin_amdgcn_mfma_f32_16x16x32_bf16(
            af[mi], bfv[ni], acc[mi][ni], 0, 0, 0);
    __syncthreads();
  }
  // C store: D row = (lane>>4)*4 + reg, col = lane&15
#pragma unroll
  for (int mi = 0; mi < 2; ++mi)
#pragma unroll
    for (int rr = 0; rr < 4; ++rr) {
      int row = bm + wm + mi * 16 + lq * 4 + rr;
      if (row < M) {
#pragma unroll
        for (int ni = 0; ni < 2; ++ni) {
          int col = bn + wn + ni * 16 + l16;
          C[(size_t)row * ldc + col] = f2b(acc[mi][ni][rr]);
        }
      }
    }
  if (DOTS) {
    int head = blockIdx.x;
    float ps[2][4], pd[2][4];
#pragma unroll
    for (int mi = 0; mi < 2; ++mi)
#pragma unroll
      for (int rr = 0; rr < 4; ++rr) {
        float s = 0.f, d = 0.f;
#pragma unroll
        for (int ni = 0; ni < 2; ++ni) {
          int col = wn + ni * 16 + l16;
          s += acc[mi][ni][rr] * ws[head * 64 + col];
          d += acc[mi][ni][rr] * wd[head * 64 + col];
        }
        ps[mi][rr] = s;
        pd[mi][rr] = d;
      }
#pragma unroll
    for (int off = 1; off < 16; off <<= 1)
#pragma unroll
      for (int mi = 0; mi < 2; ++mi)
#pragma unroll
        for (int rr = 0; rr < 4; ++rr) {
          ps[mi][rr] += __shfl_xor(ps[mi][rr], off);
          pd[mi][rr] += __shfl_xor(pd[mi][rr], off);
        }
    if (l16 == 0) {
#pragma unroll
      for (int mi = 0; mi < 2; ++mi)
#pragma unroll
        for (int rr = 0; rr < 4; ++rr) {
          int rl = wm + mi * 16 + lq * 4 + rr;
          atomicAdd(&sdot[rl], ps[mi][rr]);
          atomicAdd(&ddot[rl], pd[mi][rr]);
        }
    }
    __syncthreads();
    if (t < 64 && bm + t < M) {
      as_[(size_t)(bm + t) * H + head] = sdot[t];
      ad_[(size_t)(bm + t) * H + head] = ddot[t];
    }
  }
}

// ---------------- GAT layer-1 aggregation: 1 wave per node, 4 heads -------
__global__ __launch_bounds__(256) void gat_agg4_k(
    const int* __restrict__ offsets, const int2* __restrict__ csr,
    const unsigned short* __restrict__ h, const float* __restrict__ as_,
    const float* __restrict__ ad_, const float* __restrict__ bias,
    unsigned short* __restrict__ out) {
  __shared__ float exs[4][64][4];
  __shared__ int srcs[4][64];
  int wvx = threadIdx.x >> 6, lane = threadIdx.x & 63;
  int n = blockIdx.x * 4 + wvx;
  int hd = lane >> 4;
  int beg = offsets[n], end = offsets[n + 1];
  float4 adn = *(const float4*)(ad_ + (size_t)n * 4);
  float m0 = -1e30f, m1 = -1e30f, m2 = -1e30f, m3 = -1e30f;
  float d0 = 0.f, d1 = 0.f, d2 = 0.f, d3 = 0.f;
  float4 acc = {0.f, 0.f, 0.f, 0.f};
  for (int base = beg; base < end; base += 64) {
    int cnt = min(64, end - base);
    int src = 0;
    float l0 = -1e30f, l1 = -1e30f, l2 = -1e30f, l3 = -1e30f;
    if (lane < cnt) {
      src = csr[base + lane].x;
      float4 a4 = *(const float4*)(as_ + (size_t)src * 4);
      float t;
      t = a4.x + adn.x; l0 = (t > 0.f) ? t : NEG * t;
      t = a4.y + adn.y; l1 = (t > 0.f) ? t : NEG * t;
      t = a4.z + adn.z; l2 = (t > 0.f) ? t : NEG * t;
      t = a4.w + adn.w; l3 = (t > 0.f) ? t : NEG * t;
    }
    float t0 = l0, t1 = l1, t2 = l2, t3 = l3;
#pragma unroll
    for (int off = 32; off; off >>= 1) {
      t0 = fmaxf(t0, __shfl_xor(t0, off));
      t1 = fmaxf(t1, __shfl_xor(t1, off));
      t2 = fmaxf(t2, __shfl_xor(t2, off));
      t3 = fmaxf(t3, __shfl_xor(t3, off));
    }
    float M0 = fmaxf(m0, t0), M1 = fmaxf(m1, t1), M2 = fmaxf(m2, t2), M3 = fmaxf(m3, t3);
    float e0 = 0.f, e1 = 0.f, e2 = 0.f, e3 = 0.f;
    if (lane < cnt) {
      e0 = __expf(l0 - M0); e1 = __expf(l1 - M1);
      e2 = __expf(l2 - M2); e3 = __expf(l3 - M3);
    }
    float s0 = e0, s1 = e1, s2 = e2, s3 = e3;
#pragma unroll
    for (int off = 32; off; off >>= 1) {
      s0 += __shfl_xor(s0, off);
      s1 += __shfl_xor(s1, off);
      s2 += __shfl_xor(s2, off);
      s3 += __shfl_xor(s3, off);
    }
    float sc0 = __expf(m0 - M0), sc1 = __expf(m1 - M1);
    float sc2 = __expf(m2 - M2), sc3 = __expf(m3 - M3);
    d0 = d0 * sc0 + s0; d1 = d1 * sc1 + s1;
    d2 = d2 * sc2 + s2; d3 = d3 * sc3 + s3;
    m0 = M0; m1 = M1; m2 = M2; m3 = M3;
    float mysc = (hd == 0) ? sc0 : (hd == 1) ? sc1 : (hd == 2) ? sc2 : sc3;
    acc.x *= mysc; acc.y *= mysc; acc.z *= mysc; acc.w *= mysc;
    float4 ex4 = {e0, e1, e2, e3};
    *(float4*)(&exs[wvx][lane][0]) = ex4;
    srcs[wvx][lane] = src;
    __builtin_amdgcn_wave_barrier();
    int e = 0;
    for (; e + 8 <= cnt; e += 8) {
      ushort4 r[8];
      float w[8];
#pragma unroll
      for (int j = 0; j < 8; ++j) {
        int si = srcs[wvx][e + j];
        w[j] = exs[wvx][e + j][hd];
        r[j] = *(const ushort4*)(h + (size_t)si * 256 + lane * 4);
      }
#pragma unroll
      for (int j = 0; j < 8; ++j) {
        acc.x += w[j] * bf2f(r[j].x); acc.y += w[j] * bf2f(r[j].y);
        acc.z += w[j] * bf2f(r[j].z); acc.w += w[j] * bf2f(r[j].w);
      }
    }
    for (; e < cnt; ++e) {
      int si = srcs[wvx][e];
      float w = exs[wvx][e][hd];
      ushort4 r = *(const ushort4*)(h + (size_t)si * 256 + lane * 4);
      acc.x += w * bf2f(r.x); acc.y += w * bf2f(r.y);
      acc.z += w * bf2f(r.z); acc.w += w * bf2f(r.w);
    }
  }
  float myden = (hd == 0) ? d0 : (hd == 1) ? d1 : (hd == 2) ? d2 : d3;
  float4 b4 = *(const float4*)(bias + lane * 4);
  float4 res;
  res.x = acc.x / myden + b4.x;
  res.y = acc.y / myden + b4.y;
  res.z = acc.z / myden + b4.z;
  res.w = acc.w / myden + b4.w;
  res.x = (res.x > 0.f) ? res.x : (__expf(res.x) - 1.f);
  res.y = (res.y > 0.f) ? res.y : (__expf(res.y) - 1.f);
  res.z = (res.z > 0.f) ? res.z : (__expf(res.z) - 1.f);
  res.w = (res.w > 0.f) ? res.w : (__expf(res.w) - 1.f);
  ushort4 ov = {f2b(res.x), f2b(res.y), f2b(res.z), f2b(res.w)};
  *(ushort4*)(out + (size_t)n * 256 + lane * 4) = ov;
}

// ---------------- GAT layer-2 aggregation: 1 wave per node, H=1 ----------
__global__ __launch_bounds__(256) void gat_agg1_k(
    const int* __restrict__ offsets, const int2* __restrict__ csr,
    const unsigned short* __restrict__ h, const float* __restrict__ as_,
    const float* __restrict__ ad_, const float* __restrict__ bias,
    unsigned short* __restrict__ out) {
  __shared__ float exs[4][64];
  __shared__ int srcs[4][64];
  int wvx = threadIdx.x >> 6, lane = threadIdx.x & 63;
  int n = blockIdx.x * 4 + wvx;
  int slot = lane >> 5, cp = lane & 31;
  int beg = offsets[n], end = offsets[n + 1];
  float adn = ad_[n];
  float m = -1e30f, den = 0.f;
  float ax = 0.f, ay = 0.f;
  for (int base = beg; base < end; base += 64) {
    int cnt = min(64, end - base);
    int src = 0;
    float l = -1e30f;
    if (lane < cnt) {
      src = csr[base + lane].x;
      float t = as_[src] + adn;
      l = (t > 0.f) ? t : NEG * t;
    }
    float mt = l;
#pragma unroll
    for (int off = 32; off; off >>= 1) mt = fmaxf(mt, __shfl_xor(mt, off));
    float M = fmaxf(m, mt);
    float ex = (lane < cnt) ? __expf(l - M) : 0.f;
    float s = ex;
#pragma unroll
    for (int off = 32; off; off >>= 1) s += __shfl_xor(s, off);
    float sc = __expf(m - M);
    den = den * sc + s;
    m = M;
    ax *= sc; ay *= sc;
    exs[wvx][lane] = ex;
    srcs[wvx][lane] = src;
    __builtin_amdgcn_wave_barrier();
    int e = 0;
    for (; e + 8 <= cnt; e += 8) {
      int i0 = e + slot, i1 = e + 2 + slot, i2 = e + 4 + slot, i3 = e + 6 + slot;
      int si0 = srcs[wvx][i0], si1 = srcs[wvx][i1], si2 = srcs[wvx][i2], si3 = srcs[wvx][i3];
      float w0 = exs[wvx][i0], w1 = exs[wvx][i1], w2 = exs[wvx][i2], w3 = exs[wvx][i3];
      ushort2 r0 = *(const ushort2*)(h + (size_t)si0 * 64 + cp * 2);
      ushort2 r1 = *(const ushort2*)(h + (size_t)si1 * 64 + cp * 2);
      ushort2 r2 = *(const ushort2*)(h + (size_t)si2 * 64 + cp * 2);
      ushort2 r3 = *(const ushort2*)(h + (size_t)si3 * 64 + cp * 2);
      ax += w0 * bf2f(r0.x); ay += w0 * bf2f(r0.y);
      ax += w1 * bf2f(r1.x); ay += w1 * bf2f(r1.y);
      ax += w2 * bf2f(r2.x); ay += w2 * bf2f(r2.y);
      ax += w3 * bf2f(r3.x); ay += w3 * bf2f(r3.y);
    }
    for (; e < cnt; e += 2) {
      int i = e + slot;
      int ok = (i < cnt);
      int si = srcs[wvx][ok ? i : 0];
      float w = ok ? exs[wvx][i] : 0.f;
      ushort2 r = *(const ushort2*)(h + (size_t)si * 64 + cp * 2);
      ax += w * bf2f(r.x); ay += w * bf2f(r.y);
    }
  }
  ax += __shfl_xor(ax, 32);
  ay += __shfl_xor(ay, 32);
  if (slot == 0) {
    ushort2 ov;
    ov.x = f2b(ax / den + bias[cp * 2]);
    ov.y = f2b(ay / den + bias[cp * 2 + 1]);
    *(ushort2*)(out + (size_t)n * 64 + cp * 2) = ov;
  }
}

// ---------------- dst-grouped edge MLP: 1 wave per dst node ---------------
// slot=lane>>4 (4 edges/iter), cp=lane&15 (4 ch each). q[d]+mb1 cached in
// registers; per edge gather p[src] (ushort4/lane), relu, dot w2, 4-deep
// shfl reduce within the 16-lane group, write out[eid].
__global__ __launch_bounds__(256) void edge_out_k(
    const int* __restrict__ offsets, const int2* __restrict__ csr,
    const unsigned short* __restrict__ pq,
    const float* __restrict__ mb1, const float* __restrict__ w2,
    const float* __restrict__ mb2, float* __restrict__ out) {
  int wvx = threadIdx.x >> 6, lane = threadIdx.x & 63;
  int n = blockIdx.x * 4 + wvx;
  int slot = lane >> 4, cp = lane & 15;
  int beg = offsets[n], end = offsets[n + 1];
  ushort4 qv = *(const ushort4*)(pq + (size_t)n * 128 + 64 + cp * 4);
  float4 base4 = *(const float4*)(mb1 + cp * 4);
  base4.x += bf2f(qv.x); base4.y += bf2f(qv.y);
  base4.z += bf2f(qv.z); base4.w += bf2f(qv.w);
  float4 w4 = *(const float4*)(w2 + cp * 4);
  float b2v = mb2[0];
  for (int base = beg; base < end; base += 4) {
    int i = base + slot;
    int2 se = {0, -1};
    if (i < end) se = csr[i];
    float r = 0.f;
    if (se.y >= 0) {
      ushort4 pv = *(const ushort4*)(pq + (size_t)se.x * 128 + cp * 4);
      float v0 = fmaxf(bf2f(pv.x) + base4.x, 0.f);
      float v1 = fmaxf(bf2f(pv.y) + base4.y, 0.f);
      float v2 = fmaxf(bf2f(pv.z) + base4.z, 0.f);
      float v3 = fmaxf(bf2f(pv.w) + base4.w, 0.f);
      r = v0 * w4.x + v1 * w4.y + v2 * w4.z + v3 * w4.w;
    }
    r += __shfl_xor(r, 8);
    r += __shfl_xor(r, 4);
    r += __shfl_xor(r, 2);
    r += __shfl_xor(r, 1);
    if (cp == 0 && se.y >= 0) out[se.y] = r + b2v;
  }
}

extern "C" void kernel_launch(void* const* d_in, const int* in_sizes, int n_in,
                              void* d_out, int out_size, void* d_ws, size_t ws_size,
                              hipStream_t stream) {
  const float* x = (const float*)d_in[0];
  const int* ei = (const int*)d_in[1];
  const float* W1 = (const float*)d_in[2];
  const float* as1w = (const float*)d_in[3];
  const float* ad1w = (const float*)d_in[4];
  const float* b1 = (const float*)d_in[5];
  const float* W2 = (const float*)d_in[6];
  const float* as2w = (const float*)d_in[7];
  const float* ad2w = (const float*)d_in[8];
  const float* b2 = (const float*)d_in[9];
  const float* mw1 = (const float*)d_in[10];
  const float* mb1 = (const float*)d_in[11];
  const float* mw2 = (const float*)d_in[12];
  const float* mb2 = (const float*)d_in[13];
  float* out = (float*)d_out;

  char* ws = (char*)d_ws;
  size_t o = 0;
  auto alloc = [&](size_t bytes) {
    void* ptr = ws + o;
    o += (bytes + 255) & ~(size_t)255;
    return ptr;
  };
  int* counts = (int*)alloc((size_t)NN * 4);
  int* offsets = (int*)alloc((size_t)(NN + 1) * 4);
  int* cursor = (int*)alloc((size_t)NN * 4);
  int* bsums = (int*)alloc((size_t)NB * 4);
  int2* csr = (int2*)alloc((size_t)ET * 8);
  unsigned short* xb = (unsigned short*)alloc((size_t)NN * 128 * 2);
  unsigned short* w1t = (unsigned short*)alloc((size_t)256 * 128 * 2);
  unsigned short* w2t = (unsigned short*)alloc((size_t)64 * 256 * 2);
  unsigned short* pqt = (unsigned short*)alloc((size_t)128 * 64 * 2);
  unsigned short* h1b = (unsigned short*)alloc((size_t)NN * 256 * 2);  // reused h2b/pq
  float* a_s1 = (float*)alloc((size_t)NN * 4 * 4);
  float* a_d1 = (float*)alloc((size_t)NN * 4 * 4);
  unsigned short* x2b = (unsigned short*)alloc((size_t)NN * 256 * 2);
  unsigned short* yb = (unsigned short*)alloc((size_t)NN * 64 * 2);
  unsigned short* h2b = h1b;                  // NN*64
  unsigned short* pq = h1b + (size_t)NN * 64; // NN*128, [p|q]

  // CSR build (shared by both GAT layers and edge MLP; self loops eid=-1)
  zero_counts_k<<<NB, 256, 0, stream>>>(counts);
  hist_k<<<(ET + 255) / 256, 256, 0, stream>>>(ei, counts);
  scan_bsum_k<<<NB, 256, 0, stream>>>(counts, bsums);
  scan_top_k<<<1, 256, 0, stream>>>(bsums);
  scan_final_k<<<NB, 256, 0, stream>>>(counts, bsums, offsets, cursor);
  scatter_k<<<(ET + 255) / 256, 256, 0, stream>>>(ei, cursor, csr);

  // Conversions: x -> bf16; weights -> transposed bf16
  convx_k<<<(NN * 32 + 255) / 256, 256, 0, stream>>>(x, xb, NN * 32);
  convT_k<<<(256 * 128 + 255) / 256, 256, 0, stream>>>(W1, w1t, 128, 256);
  convT_k<<<(64 * 256 + 255) / 256, 256, 0, stream>>>(W2, w2t, 256, 64);
  convPQ_k<<<(128 * 64 + 255) / 256, 256, 0, stream>>>(mw1, pqt);

  int gy = (NN + 63) / 64;
  // Layer 1: h1 = x @ W1 (MFMA, bf16) + fused dots; aggregate -> x2 (bf16)
  mgemm_k<1><<<dim3(4, gy), 256, 0, stream>>>(xb, 128, w1t, 128, h1b, 256,
                                              NN, 256, 128, as1w, ad1w, a_s1, a_d1, 4);
  gat_agg4_k<<<NN / 4, 256, 0, stream>>>(offsets, csr, h1b, a_s1, a_d1, b1, x2b);

  // Layer 2: h2 = x2 @ W2 (MFMA) + fused dots; aggregate -> y (bf16)
  mgemm_k<1><<<dim3(1, gy), 256, 0, stream>>>(x2b, 256, w2t, 256, h2b, 64,
                                              NN, 64, 256, as2w, ad2w, a_s1, a_d1, 1);
  gat_agg1_k<<<NN / 4, 256, 0, stream>>>(offsets, csr, h2b, a_s1, a_d1, b2, yb);

  // Edge MLP: pq = y @ [mw1[:64] | mw1[64:]]  (one MFMA GEMM, N=128)
  mgemm_k<0><<<dim3(2, gy), 256, 0, stream>>>(yb, 64, pqt, 64, pq, 128,
                                              NN, 128, 64, nullptr, nullptr,
                                              nullptr, nullptr, 0);

  // Final per-edge output (dst-grouped)
  edge_out_k<<<NN / 4, 256, 0, stream>>>(offsets, csr, pq, mb1, mw2, mb2, out);
}

// Round 7
// 295.320 us; speedup vs baseline: 2.5832x; 1.0402x over previous
//
#include <hip/hip_runtime.h>
#include <hip/hip_bf16.h>
#include <math.h>

#define NN 50000
#define NE 800000
#define NB ((NN + 255) / 256)
#define NEG 0.2f

typedef __hip_bfloat16 bf16;
typedef __attribute__((ext_vector_type(8))) short s8v;
typedef __attribute__((ext_vector_type(4))) float f4v;

__device__ __forceinline__ float bf2f(unsigned short u) {
  union { unsigned int i; float f; } c;
  c.i = ((unsigned int)u) << 16;
  return c.f;
}
__device__ __forceinline__ float blo(unsigned int u) {
  union { unsigned int i; float f; } c;
  c.i = u << 16;
  return c.f;
}
__device__ __forceinline__ float bhi(unsigned int u) {
  union { unsigned int i; float f; } c;
  c.i = u & 0xffff0000u;
  return c.f;
}
__device__ __forceinline__ unsigned short f2b(float f) {
  bf16 b = __float2bfloat16(f);
  return __builtin_bit_cast(unsigned short, b);
}
__device__ __forceinline__ float lrelu(float t) { return (t > 0.f) ? t : NEG * t; }

// ---------------- CSR build (real edges only; self-loops analytic) --------
__global__ void zero_counts_k(int* __restrict__ c) {
  int i = blockIdx.x * 256 + threadIdx.x;
  if (i < NN) c[i] = 0;
}

__global__ void hist_k(const int* __restrict__ ei, int* __restrict__ counts) {
  int e = blockIdx.x * 256 + threadIdx.x;
  if (e >= NE) return;
  atomicAdd(&counts[ei[NE + e]], 1);
}

__global__ __launch_bounds__(256) void scan_bsum_k(const int* __restrict__ counts,
                                                   int* __restrict__ bsums) {
  __shared__ int wsum[4];
  int i = blockIdx.x * 256 + threadIdx.x;
  int v = (i < NN) ? counts[i] : 0;
#pragma unroll
  for (int off = 32; off; off >>= 1) v += __shfl_xor(v, off);
  if ((threadIdx.x & 63) == 0) wsum[threadIdx.x >> 6] = v;
  __syncthreads();
  if (threadIdx.x == 0) bsums[blockIdx.x] = wsum[0] + wsum[1] + wsum[2] + wsum[3];
}

__global__ __launch_bounds__(256) void scan_top_k(int* __restrict__ bsums) {
  __shared__ int s[256];
  int t = threadIdx.x;
  int v = (t < NB) ? bsums[t] : 0;
  s[t] = v;
  __syncthreads();
  for (int off = 1; off < 256; off <<= 1) {
    int u = (t >= off) ? s[t - off] : 0;
    __syncthreads();
    s[t] += u;
    __syncthreads();
  }
  if (t < NB) bsums[t] = s[t] - v;  // exclusive
}

__global__ __launch_bounds__(256) void scan_final_k(const int* __restrict__ counts,
                                                    const int* __restrict__ bsums,
                                                    int* __restrict__ offsets,
                                                    int* __restrict__ cursor) {
  __shared__ int s[256];
  int t = threadIdx.x;
  int i = blockIdx.x * 256 + t;
  int v = (i < NN) ? counts[i] : 0;
  s[t] = v;
  __syncthreads();
  for (int off = 1; off < 256; off <<= 1) {
    int u = (t >= off) ? s[t - off] : 0;
    __syncthreads();
    s[t] += u;
    __syncthreads();
  }
  int excl = s[t] - v + bsums[blockIdx.x];
  if (i < NN) {
    offsets[i] = excl;
    cursor[i] = excl;
    if (i == NN - 1) offsets[NN] = excl + v;
  }
}

__global__ void scatter_k(const int* __restrict__ ei, int* __restrict__ cursor,
                          int2* __restrict__ csr) {
  int e = blockIdx.x * 256 + threadIdx.x;
  if (e >= NE) return;
  int s = ei[e], d = ei[NE + e];
  int pos = atomicAdd(&cursor[d], 1);
  csr[pos] = make_int2(s, e);
}

// ---------------- fp32 -> bf16 conversions ----------------
__global__ void convx_k(const float* __restrict__ in, unsigned short* __restrict__ out,
                        int n4) {
  int i = blockIdx.x * 256 + threadIdx.x;
  if (i >= n4) return;
  float4 v = *(const float4*)(in + (size_t)i * 4);
  ushort4 o = {f2b(v.x), f2b(v.y), f2b(v.z), f2b(v.w)};
  *(ushort4*)(out + (size_t)i * 4) = o;
}

__global__ void convT_k(const float* __restrict__ in, unsigned short* __restrict__ out,
                        int K, int N) {
  int i = blockIdx.x * 256 + threadIdx.x;
  if (i >= K * N) return;
  int n = i / K, k = i - n * K;
  out[i] = f2b(in[(size_t)k * N + n]);
}

__global__ void convPQ_k(const float* __restrict__ mw1, unsigned short* __restrict__ out) {
  int i = blockIdx.x * 256 + threadIdx.x;
  if (i >= 128 * 64) return;
  int n = i >> 6, k = i & 63;
  float v = (n < 64) ? mw1[(size_t)k * 64 + n] : mw1[(size_t)(64 + k) * 64 + (n - 64)];
  out[i] = f2b(v);
}

// ---------------- bf16 MFMA GEMM: C[M,N] = A[M,K] @ Bt[N,K]^T ----------------
template <int DOTS>
__global__ __launch_bounds__(256) void mgemm_k(
    const unsigned short* __restrict__ A, int lda,
    const unsigned short* __restrict__ Bt, int ldb,
    unsigned short* __restrict__ C, int ldc,
    int M, int N, int K,
    const float* __restrict__ ws, const float* __restrict__ wd,
    float* __restrict__ as_, float* __restrict__ ad_, int H) {
  __shared__ unsigned short Asl[64][40];
  __shared__ unsigned short Btl[64][40];
  __shared__ float sdot[64], ddot[64];
  int bm = blockIdx.y * 64, bn = blockIdx.x * 64;
  int t = threadIdx.x;
  int wv = t >> 6, lane = t & 63;
  int wm = (wv >> 1) * 32, wn = (wv & 1) * 32;
  int l16 = lane & 15, lq = lane >> 4;
  if (DOTS && t < 64) { sdot[t] = 0.f; ddot[t] = 0.f; }
  f4v acc[2][2];
#pragma unroll
  for (int mi = 0; mi < 2; ++mi)
#pragma unroll
    for (int ni = 0; ni < 2; ++ni) {
      acc[mi][ni][0] = 0.f; acc[mi][ni][1] = 0.f;
      acc[mi][ni][2] = 0.f; acc[mi][ni][3] = 0.f;
    }
  int sr = t >> 2, sc = (t & 3) * 8;
  for (int k0 = 0; k0 < K; k0 += 32) {
    uint4 av = {0, 0, 0, 0};
    int gr = bm + sr;
    if (gr < M) av = *(const uint4*)(A + (size_t)gr * lda + k0 + sc);
    *(uint4*)&Asl[sr][sc] = av;
    uint4 bv = *(const uint4*)(Bt + (size_t)(bn + sr) * ldb + k0 + sc);
    *(uint4*)&Btl[sr][sc] = bv;
    __syncthreads();
    s8v af[2], bfv[2];
#pragma unroll
    for (int mi = 0; mi < 2; ++mi)
      af[mi] = *(const s8v*)&Asl[wm + mi * 16 + l16][lq * 8];
#pragma unroll
    for (int ni = 0; ni < 2; ++ni)
      bfv[ni] = *(const s8v*)&Btl[wn + ni * 16 + l16][lq * 8];
#pragma unroll
    for (int mi = 0; mi < 2; ++mi)
#pragma unroll
      for (int ni = 0; ni < 2; ++ni)
        acc[mi][ni] = __builtin_amdgcn_mfma_f32_16x16x32_bf16(
            af[mi], bfv[ni], acc[mi][ni], 0, 0, 0);
    __syncthreads();
  }
#pragma unroll
  for (int mi = 0; mi < 2; ++mi)
#pragma unroll
    for (int rr = 0; rr < 4; ++rr) {
      int row = bm + wm + mi * 16 + lq * 4 + rr;
      if (row < M) {
#pragma unroll
        for (int ni = 0; ni < 2; ++ni) {
          int col = bn + wn + ni * 16 + l16;
          C[(size_t)row * ldc + col] = f2b(acc[mi][ni][rr]);
        }
      }
    }
  if (DOTS) {
    int head = blockIdx.x;
    float ps[2][4], pd[2][4];
#pragma unroll
    for (int mi = 0; mi < 2; ++mi)
#pragma unroll
      for (int rr = 0; rr < 4; ++rr) {
        float s = 0.f, d = 0.f;
#pragma unroll
        for (int ni = 0; ni < 2; ++ni) {
          int col = wn + ni * 16 + l16;
          s += acc[mi][ni][rr] * ws[head * 64 + col];
          d += acc[mi][ni][rr] * wd[head * 64 + col];
        }
        ps[mi][rr] = s;
        pd[mi][rr] = d;
      }
#pragma unroll
    for (int off = 1; off < 16; off <<= 1)
#pragma unroll
      for (int mi = 0; mi < 2; ++mi)
#pragma unroll
        for (int rr = 0; rr < 4; ++rr) {
          ps[mi][rr] += __shfl_xor(ps[mi][rr], off);
          pd[mi][rr] += __shfl_xor(pd[mi][rr], off);
        }
    if (l16 == 0) {
#pragma unroll
      for (int mi = 0; mi < 2; ++mi)
#pragma unroll
        for (int rr = 0; rr < 4; ++rr) {
          int rl = wm + mi * 16 + lq * 4 + rr;
          atomicAdd(&sdot[rl], ps[mi][rr]);
          atomicAdd(&ddot[rl], pd[mi][rr]);
        }
    }
    __syncthreads();
    if (t < 64 && bm + t < M) {
      as_[(size_t)(bm + t) * H + head] = sdot[t];
      ad_[(size_t)(bm + t) * H + head] = ddot[t];
    }
  }
}

// ---------------- GAT layer-1 aggregation: 1 wave per node, 4 heads -------
// No max-subtraction (|logit|<~7, exp safe in fp32); self-loop analytic.
__global__ __launch_bounds__(256) void gat_agg4_k(
    const int* __restrict__ offsets, const int2* __restrict__ csr,
    const unsigned short* __restrict__ h, const float* __restrict__ as_,
    const float* __restrict__ ad_, const float* __restrict__ bias,
    unsigned short* __restrict__ out) {
  __shared__ float exs[4][64][4];
  __shared__ int srcs[4][64];
  int wvx = threadIdx.x >> 6, lane = threadIdx.x & 63;
  int n = blockIdx.x * 4 + wvx;
  int hd = lane >> 4;
  int beg = offsets[n], end = offsets[n + 1];
  float4 adn = *(const float4*)(ad_ + (size_t)n * 4);
  float4 asn = *(const float4*)(as_ + (size_t)n * 4);
  // self-loop term
  float es0 = __expf(lrelu(asn.x + adn.x));
  float es1 = __expf(lrelu(asn.y + adn.y));
  float es2 = __expf(lrelu(asn.z + adn.z));
  float es3 = __expf(lrelu(asn.w + adn.w));
  float d0 = es0, d1 = es1, d2 = es2, d3 = es3;
  float wself = (hd == 0) ? es0 : (hd == 1) ? es1 : (hd == 2) ? es2 : es3;
  uint2 sv = *(const uint2*)(h + (size_t)n * 256 + lane * 4);
  float2 a01, a23;
  a01.x = wself * blo(sv.x); a01.y = wself * bhi(sv.x);
  a23.x = wself * blo(sv.y); a23.y = wself * bhi(sv.y);
  for (int base = beg; base < end; base += 64) {
    int cnt = min(64, end - base);
    int src = 0;
    float e0 = 0.f, e1 = 0.f, e2 = 0.f, e3 = 0.f;
    if (lane < cnt) {
      src = csr[base + lane].x;
      float4 a4 = *(const float4*)(as_ + (size_t)src * 4);
      e0 = __expf(lrelu(a4.x + adn.x));
      e1 = __expf(lrelu(a4.y + adn.y));
      e2 = __expf(lrelu(a4.z + adn.z));
      e3 = __expf(lrelu(a4.w + adn.w));
    }
    float s0 = e0, s1 = e1, s2 = e2, s3 = e3;
#pragma unroll
    for (int off = 32; off; off >>= 1) {
      s0 += __shfl_xor(s0, off);
      s1 += __shfl_xor(s1, off);
      s2 += __shfl_xor(s2, off);
      s3 += __shfl_xor(s3, off);
    }
    d0 += s0; d1 += s1; d2 += s2; d3 += s3;
    float4 ex4 = {e0, e1, e2, e3};
    *(float4*)(&exs[wvx][lane][0]) = ex4;
    srcs[wvx][lane] = src;
    __builtin_amdgcn_wave_barrier();
    int e = 0;
    for (; e + 8 <= cnt; e += 8) {
      uint2 r[8];
      float w[8];
#pragma unroll
      for (int j = 0; j < 8; ++j) {
        int si = srcs[wvx][e + j];
        w[j] = exs[wvx][e + j][hd];
        r[j] = *(const uint2*)(h + (size_t)si * 256 + lane * 4);
      }
#pragma unroll
      for (int j = 0; j < 8; ++j) {
        a01.x += w[j] * blo(r[j].x); a01.y += w[j] * bhi(r[j].x);
        a23.x += w[j] * blo(r[j].y); a23.y += w[j] * bhi(r[j].y);
      }
    }
    for (; e < cnt; ++e) {
      int si = srcs[wvx][e];
      float w = exs[wvx][e][hd];
      uint2 r = *(const uint2*)(h + (size_t)si * 256 + lane * 4);
      a01.x += w * blo(r.x); a01.y += w * bhi(r.x);
      a23.x += w * blo(r.y); a23.y += w * bhi(r.y);
    }
  }
  float myden = (hd == 0) ? d0 : (hd == 1) ? d1 : (hd == 2) ? d2 : d3;
  float inv = 1.f / myden;
  float4 b4 = *(const float4*)(bias + lane * 4);
  float4 res;
  res.x = a01.x * inv + b4.x;
  res.y = a01.y * inv + b4.y;
  res.z = a23.x * inv + b4.z;
  res.w = a23.y * inv + b4.w;
  res.x = (res.x > 0.f) ? res.x : (__expf(res.x) - 1.f);
  res.y = (res.y > 0.f) ? res.y : (__expf(res.y) - 1.f);
  res.z = (res.z > 0.f) ? res.z : (__expf(res.z) - 1.f);
  res.w = (res.w > 0.f) ? res.w : (__expf(res.w) - 1.f);
  ushort4 ov = {f2b(res.x), f2b(res.y), f2b(res.z), f2b(res.w)};
  *(ushort4*)(out + (size_t)n * 256 + lane * 4) = ov;
}

// ---------------- GAT layer-2 aggregation: 1 wave per node, H=1 ----------
__global__ __launch_bounds__(256) void gat_agg1_k(
    const int* __restrict__ offsets, const int2* __restrict__ csr,
    const unsigned short* __restrict__ h, const float* __restrict__ as_,
    const float* __restrict__ ad_, const float* __restrict__ bias,
    unsigned short* __restrict__ out) {
  __shared__ float exs[4][64];
  __shared__ int srcs[4][64];
  int wvx = threadIdx.x >> 6, lane = threadIdx.x & 63;
  int n = blockIdx.x * 4 + wvx;
  int slot = lane >> 5, cp = lane & 31;
  int beg = offsets[n], end = offsets[n + 1];
  float adn = ad_[n];
  float eself = __expf(lrelu(as_[n] + adn));
  float den = eself;
  float ax = 0.f, ay = 0.f;
  if (slot == 0) {
    unsigned int sv = *(const unsigned int*)(h + (size_t)n * 64 + cp * 2);
    ax = eself * blo(sv);
    ay = eself * bhi(sv);
  }
  for (int base = beg; base < end; base += 64) {
    int cnt = min(64, end - base);
    int src = 0;
    float ex = 0.f;
    if (lane < cnt) {
      src = csr[base + lane].x;
      ex = __expf(lrelu(as_[src] + adn));
    }
    float s = ex;
#pragma unroll
    for (int off = 32; off; off >>= 1) s += __shfl_xor(s, off);
    den += s;
    exs[wvx][lane] = ex;
    srcs[wvx][lane] = src;
    __builtin_amdgcn_wave_barrier();
    int e = 0;
    for (; e + 8 <= cnt; e += 8) {
      int i0 = e + slot, i1 = e + 2 + slot, i2 = e + 4 + slot, i3 = e + 6 + slot;
      int si0 = srcs[wvx][i0], si1 = srcs[wvx][i1], si2 = srcs[wvx][i2], si3 = srcs[wvx][i3];
      float w0 = exs[wvx][i0], w1 = exs[wvx][i1], w2 = exs[wvx][i2], w3 = exs[wvx][i3];
      unsigned int r0 = *(const unsigned int*)(h + (size_t)si0 * 64 + cp * 2);
      unsigned int r1 = *(const unsigned int*)(h + (size_t)si1 * 64 + cp * 2);
      unsigned int r2 = *(const unsigned int*)(h + (size_t)si2 * 64 + cp * 2);
      unsigned int r3 = *(const unsigned int*)(h + (size_t)si3 * 64 + cp * 2);
      ax += w0 * blo(r0); ay += w0 * bhi(r0);
      ax += w1 * blo(r1); ay += w1 * bhi(r1);
      ax += w2 * blo(r2); ay += w2 * bhi(r2);
      ax += w3 * blo(r3); ay += w3 * bhi(r3);
    }
    for (; e < cnt; e += 2) {
      int i = e + slot;
      int ok = (i < cnt);
      int si = srcs[wvx][ok ? i : 0];
      float w = ok ? exs[wvx][i] : 0.f;
      unsigned int r = *(const unsigned int*)(h + (size_t)si * 64 + cp * 2);
      ax += w * blo(r); ay += w * bhi(r);
    }
  }
  ax += __shfl_xor(ax, 32);
  ay += __shfl_xor(ay, 32);
  if (slot == 0) {
    float inv = 1.f / den;
    ushort2 ov;
    ov.x = f2b(ax * inv + bias[cp * 2]);
    ov.y = f2b(ay * inv + bias[cp * 2 + 1]);
    *(ushort2*)(out + (size_t)n * 64 + cp * 2) = ov;
  }
}

// ---------------- dst-grouped edge MLP: 1 wave per dst node ---------------
__global__ __launch_bounds__(256) void edge_out_k(
    const int* __restrict__ offsets, const int2* __restrict__ csr,
    const unsigned short* __restrict__ pq,
    const float* __restrict__ mb1, const float* __restrict__ w2,
    const float* __restrict__ mb2, float* __restrict__ out) {
  int wvx = threadIdx.x >> 6, lane = threadIdx.x & 63;
  int n = blockIdx.x * 4 + wvx;
  int slot = lane >> 4, cp = lane & 15;
  int beg = offsets[n], end = offsets[n + 1];
  ushort4 qv = *(const ushort4*)(pq + (size_t)n * 128 + 64 + cp * 4);
  float4 base4 = *(const float4*)(mb1 + cp * 4);
  base4.x += bf2f(qv.x); base4.y += bf2f(qv.y);
  base4.z += bf2f(qv.z); base4.w += bf2f(qv.w);
  float4 w4 = *(const float4*)(w2 + cp * 4);
  float b2v = mb2[0];
  for (int base = beg; base < end; base += 4) {
    int i = base + slot;
    int2 se = {0, 0};
    bool ok = (i < end);
    if (ok) se = csr[i];
    float r = 0.f;
    if (ok) {
      ushort4 pv = *(const ushort4*)(pq + (size_t)se.x * 128 + cp * 4);
      float v0 = fmaxf(bf2f(pv.x) + base4.x, 0.f);
      float v1 = fmaxf(bf2f(pv.y) + base4.y, 0.f);
      float v2 = fmaxf(bf2f(pv.z) + base4.z, 0.f);
      float v3 = fmaxf(bf2f(pv.w) + base4.w, 0.f);
      r = v0 * w4.x + v1 * w4.y + v2 * w4.z + v3 * w4.w;
    }
    r += __shfl_xor(r, 8);
    r += __shfl_xor(r, 4);
    r += __shfl_xor(r, 2);
    r += __shfl_xor(r, 1);
    if (cp == 0 && ok) out[se.y] = r + b2v;
  }
}

extern "C" void kernel_launch(void* const* d_in, const int* in_sizes, int n_in,
                              void* d_out, int out_size, void* d_ws, size_t ws_size,
                              hipStream_t stream) {
  const float* x = (const float*)d_in[0];
  const int* ei = (const int*)d_in[1];
  const float* W1 = (const float*)d_in[2];
  const float* as1w = (const float*)d_in[3];
  const float* ad1w = (const float*)d_in[4];
  const float* b1 = (const float*)d_in[5];
  const float* W2 = (const float*)d_in[6];
  const float* as2w = (const float*)d_in[7];
  const float* ad2w = (const float*)d_in[8];
  const float* b2 = (const float*)d_in[9];
  const float* mw1 = (const float*)d_in[10];
  const float* mb1 = (const float*)d_in[11];
  const float* mw2 = (const float*)d_in[12];
  const float* mb2 = (const float*)d_in[13];
  float* out = (float*)d_out;

  char* ws = (char*)d_ws;
  size_t o = 0;
  auto alloc = [&](size_t bytes) {
    void* ptr = ws + o;
    o += (bytes + 255) & ~(size_t)255;
    return ptr;
  };
  int* counts = (int*)alloc((size_t)NN * 4);
  int* offsets = (int*)alloc((size_t)(NN + 1) * 4);
  int* cursor = (int*)alloc((size_t)NN * 4);
  int* bsums = (int*)alloc((size_t)NB * 4);
  int2* csr = (int2*)alloc((size_t)NE * 8);
  unsigned short* xb = (unsigned short*)alloc((size_t)NN * 128 * 2);
  unsigned short* w1t = (unsigned short*)alloc((size_t)256 * 128 * 2);
  unsigned short* w2t = (unsigned short*)alloc((size_t)64 * 256 * 2);
  unsigned short* pqt = (unsigned short*)alloc((size_t)128 * 64 * 2);
  unsigned short* h1b = (unsigned short*)alloc((size_t)NN * 256 * 2);  // reused h2b/pq
  float* a_s1 = (float*)alloc((size_t)NN * 4 * 4);
  float* a_d1 = (float*)alloc((size_t)NN * 4 * 4);
  unsigned short* x2b = (unsigned short*)alloc((size_t)NN * 256 * 2);
  unsigned short* yb = (unsigned short*)alloc((size_t)NN * 64 * 2);
  unsigned short* h2b = h1b;                  // NN*64
  unsigned short* pq = h1b + (size_t)NN * 64; // NN*128, [p|q]

  // CSR build (real edges only)
  zero_counts_k<<<NB, 256, 0, stream>>>(counts);
  hist_k<<<(NE + 255) / 256, 256, 0, stream>>>(ei, counts);
  scan_bsum_k<<<NB, 256, 0, stream>>>(counts, bsums);
  scan_top_k<<<1, 256, 0, stream>>>(bsums);
  scan_final_k<<<NB, 256, 0, stream>>>(counts, bsums, offsets, cursor);
  scatter_k<<<(NE + 255) / 256, 256, 0, stream>>>(ei, cursor, csr);

  // Conversions: x -> bf16; weights -> transposed bf16
  convx_k<<<(NN * 32 + 255) / 256, 256, 0, stream>>>(x, xb, NN * 32);
  convT_k<<<(256 * 128 + 255) / 256, 256, 0, stream>>>(W1, w1t, 128, 256);
  convT_k<<<(64 * 256 + 255) / 256, 256, 0, stream>>>(W2, w2t, 256, 64);
  convPQ_k<<<(128 * 64 + 255) / 256, 256, 0, stream>>>(mw1, pqt);

  int gy = (NN + 63) / 64;
  // Layer 1: h1 = x @ W1 (MFMA, bf16) + fused dots; aggregate -> x2 (bf16)
  mgemm_k<1><<<dim3(4, gy), 256, 0, stream>>>(xb, 128, w1t, 128, h1b, 256,
                                              NN, 256, 128, as1w, ad1w, a_s1, a_d1, 4);
  gat_agg4_k<<<NN / 4, 256, 0, stream>>>(offsets, csr, h1b, a_s1, a_d1, b1, x2b);

  // Layer 2: h2 = x2 @ W2 (MFMA) + fused dots; aggregate -> y (bf16)
  mgemm_k<1><<<dim3(1, gy), 256, 0, stream>>>(x2b, 256, w2t, 256, h2b, 64,
                                              NN, 64, 256, as2w, ad2w, a_s1, a_d1, 1);
  gat_agg1_k<<<NN / 4, 256, 0, stream>>>(offsets, csr, h2b, a_s1, a_d1, b2, yb);

  // Edge MLP: pq = y @ [mw1[:64] | mw1[64:]]  (one MFMA GEMM, N=128)
  mgemm_k<0><<<dim3(2, gy), 256, 0, stream>>>(yb, 64, pqt, 64, pq, 128,
                                              NN, 128, 64, nullptr, nullptr,
                                              nullptr, nullptr, 0);

  // Final per-edge output (dst-grouped)
  edge_out_k<<<NN / 4, 256, 0, stream>>>(offsets, csr, pq, mb1, mw2, mb2, out);
}